// Round 14
// baseline (804.494 us; speedup 1.0000x reference)
//
#include <hip/hip_runtime.h>
#include <math.h>

#define BATCHN 256
#define SEQ 200
#define DMODEL 256
#define DINNER 512
#define NH 32
#define HD 16
#define DSTATE 64
#define DINPROJ 1184
#define XBCLD 672
#define BL (BATCHN*SEQ)   // 51200
#define NF 101
#define XBASE 655360
#define TC 20
#define NCH 10
#define XIOFF 8500000     // f32 offset of XI within XBC arena

typedef __attribute__((ext_vector_type(8))) short bf16x8;
typedef __attribute__((ext_vector_type(4))) float f32x4;

__device__ inline unsigned short f2bf(float f) {
    union { float f; unsigned u; } v; v.f = f;
    unsigned r = v.u + 0x7FFFu + ((v.u >> 16) & 1u);
    return (unsigned short)(r >> 16);
}
__device__ inline float bf2f(unsigned short h) {
    union { unsigned u; float f; } v; v.u = ((unsigned)h) << 16;
    return v.f;
}

#define GLOAD16(src, dst) __builtin_amdgcn_global_load_lds( \
    (const __attribute__((address_space(1))) void*)(src),   \
    (__attribute__((address_space(3))) void*)(dst), 16, 0, 0)

// ---------------- DFT matrices (bf16, padded to 256) ----------------
__global__ void init_dft_kernel(unsigned short* __restrict__ EF, unsigned short* __restrict__ EI)
{
    const float ang = 6.28318530717958647692f / 200.0f;
    int idx = blockIdx.x * 256 + threadIdx.x;
    if (idx < 256 * SEQ) {
        int f = idx / SEQ, t = idx - f * SEQ;
        float v;
        if (f <= 100) { int ph = (f * t) % 200; v = cosf(ang * (float)ph); }
        else if (f <= 201) { int ff = f - 101; int ph = (ff * t) % 200; v = -sinf(ang * (float)ph); }
        else v = 0.f;
        EF[idx] = f2bf(v);
    } else if (idx < 256 * SEQ + 256 * 256) {
        int j2 = idx - 256 * SEQ;
        int t = j2 >> 8, j = j2 & 255;
        float v;
        if (t >= 200) v = 0.f;
        else if (j == 0) v = 1.0f / 200.0f;
        else if (j == 100) v = ((t & 1) ? -1.0f : 1.0f) / 200.0f;
        else if (j < 100) { int ph = (j * t) % 200; v = 2.0f * cosf(ang * (float)ph) / 200.0f; }
        else if (j >= 202 || j == 101 || j == 201) v = 0.0f;
        else { int f = j - 101; int ph = (f * t) % 200; v = -2.0f * sinf(ang * (float)ph) / 200.0f; }
        EI[j2] = f2bf(v);
    }
}

// ---------------- merged setup: weight packs + x->bf16 ----------------
#define S0 303104   // wTall 1184*256
#define S1 131072   // opwT 256*512
#define S2 262144   // w1T 1024*256
#define S3 262144   // w2T 256*1024
#define S4 1638400  // f2bf groups of 8
__global__ void setup_kernel(const float* __restrict__ ipw, const float* __restrict__ opw,
                             const float* __restrict__ w1, const float* __restrict__ w2,
                             const float* __restrict__ X,
                             unsigned short* __restrict__ wTall, unsigned short* __restrict__ opwT,
                             unsigned short* __restrict__ w1T, unsigned short* __restrict__ w2T,
                             unsigned short* __restrict__ xbf)
{
    long long idx = (long long)blockIdx.x * 256 + threadIdx.x;
    if (idx < S0) { int n = (int)(idx / 256), k = (int)(idx % 256);
        wTall[idx] = f2bf(ipw[(long long)k * DINPROJ + n]); return; }
    idx -= S0;
    if (idx < S1) { int n = (int)(idx / 512), k = (int)(idx % 512);
        opwT[idx] = f2bf(opw[(long long)k * 256 + n]); return; }
    idx -= S1;
    if (idx < S2) { int n = (int)(idx / 256), k = (int)(idx % 256);
        w1T[idx] = f2bf(w1[(long long)k * 1024 + n]); return; }
    idx -= S2;
    if (idx < S3) { int n = (int)(idx / 1024), k = (int)(idx % 1024);
        w2T[idx] = f2bf(w2[(long long)k * 256 + n]); return; }
    idx -= S3;
    if (idx < S4) {
        long long i = idx * 8;
        float4 a = ((const float4*)(X + i))[0];
        float4 b = ((const float4*)(X + i))[1];
        uint4 o;
        o.x = (unsigned)f2bf(a.x) | ((unsigned)f2bf(a.y) << 16);
        o.y = (unsigned)f2bf(a.z) | ((unsigned)f2bf(a.w) << 16);
        o.z = (unsigned)f2bf(b.x) | ((unsigned)f2bf(b.y) << 16);
        o.w = (unsigned)f2bf(b.z) | ((unsigned)f2bf(b.w) << 16);
        *(uint4*)(xbf + i) = o;
    }
}

// ---------------- x transpose: xT[b][d][t] = bf16(x[b][t][d]) ----------------
__global__ void xT_kernel(const float* __restrict__ X, unsigned short* __restrict__ XT)
{
    __shared__ float tile[32][33];
    int b = blockIdx.z, t0 = blockIdx.x * 32, d0 = blockIdx.y * 32;
    int tx = threadIdx.x & 31, ty = threadIdx.x >> 5;
    const float* xb = X + (long long)b * SEQ * DMODEL;
#pragma unroll
    for (int i = 0; i < 4; i++) {
        int t = t0 + ty + i * 8;
        tile[ty + i * 8][tx] = (t < SEQ) ? xb[(long long)t * DMODEL + d0 + tx] : 0.f;
    }
    __syncthreads();
    unsigned short* xtb = XT + (long long)b * DMODEL * SEQ;
#pragma unroll
    for (int i = 0; i < 4; i++) {
        int d = d0 + ty + i * 8;
        int t = t0 + tx;
        if (t < SEQ) xtb[(long long)d * SEQ + t] = f2bf(tile[tx][ty + i * 8]);
    }
}

// ---------------- bf16 MFMA GEMM: BK=64, gload_lds, 2x[128][32] subtile LDS ----------------
template<int ACT, int CBF>
__global__ __launch_bounds__(256) void mgemm_kernel(
    const unsigned short* __restrict__ Ab, const unsigned short* __restrict__ BTp,
    void* __restrict__ Cp, const float* __restrict__ bias,
    int M, int N, int K, int lda, int ldbt, int ldc,
    long long sA, long long sBT, long long sC)
{
    __shared__ unsigned short As[128 * 64];
    __shared__ unsigned short Bs[128 * 64];
    const unsigned short* Aa = Ab + (long long)blockIdx.z * sA;
    const unsigned short* Bt = BTp + (long long)blockIdx.z * sBT;
    float* Cf = (float*)Cp + (CBF ? 0 : (long long)blockIdx.z * sC);
    unsigned short* Cb = (unsigned short*)Cp + (CBF ? (long long)blockIdx.z * sC : 0);

    int m0 = blockIdx.y * 128, n0 = blockIdx.x * 128;
    int tid = threadIdx.x;
    int w = tid >> 6, l = tid & 63;
    int wr = w >> 1, wc = w & 1;
    int fr = l & 15, fk = l >> 4;
    // gload mapping: GLOAD q -> rows (w&1)*64 + q*16 + (l>>2), col (w>>1)*32 + (l&3)*8
    int grow = (w & 1) * 64 + (l >> 2);
    int gcol = (w >> 1) * 32 + (l & 3) * 8;
    // scalar edge mapping
    int srow = tid >> 1, shalf = tid & 1;
    bool fullM = (m0 + 128 <= M);
    bool fullN = (n0 + 128 <= N);

    f32x4 acc[4][4] = {};

    for (int k0 = 0; k0 < K; k0 += 64) {
        bool kedge = (k0 + 64 > K);
        if (fullM && !kedge) {
#pragma unroll
            for (int q = 0; q < 4; q++)
                GLOAD16(Aa + (long long)(m0 + grow + q * 16) * lda + k0 + gcol,
                        &As[w * 2048 + q * 512]);
        } else {
            int gm = m0 + srow;
            unsigned short* dst = &As[shalf * 4096 + srow * 32];
#pragma unroll
            for (int i = 0; i < 32; i++) {
                int gk = k0 + shalf * 32 + i;
                dst[i] = (gm < M && gk < K) ? Aa[(long long)gm * lda + gk] : (unsigned short)0;
            }
        }
        if (fullN && !kedge) {
#pragma unroll
            for (int q = 0; q < 4; q++)
                GLOAD16(Bt + (long long)(n0 + grow + q * 16) * ldbt + k0 + gcol,
                        &Bs[w * 2048 + q * 512]);
        } else {
            int gn = n0 + srow;
            unsigned short* dst = &Bs[shalf * 4096 + srow * 32];
#pragma unroll
            for (int i = 0; i < 32; i++) {
                int gk = k0 + shalf * 32 + i;
                dst[i] = (gn < N && gk < K) ? Bt[(long long)gn * ldbt + gk] : (unsigned short)0;
            }
        }
        __syncthreads();
#pragma unroll
        for (int s = 0; s < 2; s++) {
            bf16x8 a[4], b[4];
#pragma unroll
            for (int i = 0; i < 4; i++) {
                a[i] = *(const bf16x8*)&As[s * 4096 + (wr * 64 + i * 16 + fr) * 32 + fk * 8];
                b[i] = *(const bf16x8*)&Bs[s * 4096 + (wc * 64 + i * 16 + fr) * 32 + fk * 8];
            }
#pragma unroll
            for (int i = 0; i < 4; i++)
#pragma unroll
                for (int j = 0; j < 4; j++)
                    acc[i][j] = __builtin_amdgcn_mfma_f32_16x16x32_bf16(a[i], b[j], acc[i][j], 0, 0, 0);
        }
        __syncthreads();
    }

#pragma unroll
    for (int i = 0; i < 4; i++) {
        int gr0 = m0 + wr * 64 + i * 16 + fk * 4;
#pragma unroll
        for (int j = 0; j < 4; j++) {
            int gc = n0 + wc * 64 + j * 16 + fr;
            if (gc >= N) continue;
            float bv = bias ? bias[gc] : 0.f;
#pragma unroll
            for (int r = 0; r < 4; r++) {
                int gr = gr0 + r;
                if (gr >= M) continue;
                float v = acc[i][j][r] + bv;
                if (ACT == 1) v = 0.5f * v * (1.f + erff(v * 0.70710678118654752f));
                long long ci = (long long)gr * ldc + gc;
                if (CBF) Cb[ci] = f2bf(v);
                else Cf[ci] = v;
            }
        }
    }
}

// ---------------- merged projection GEMM (BK=64): cols<512 -> Zbf, >=512 -> XBC ----------------
__global__ __launch_bounds__(256) void mgemm_proj(
    const unsigned short* __restrict__ Aa, const unsigned short* __restrict__ Bt,
    float* __restrict__ XBCout, unsigned short* __restrict__ Zout)
{
    __shared__ unsigned short As[128 * 64];
    __shared__ unsigned short Bs[128 * 64];
    const int N = DINPROJ;
    int m0 = blockIdx.y * 128, n0 = blockIdx.x * 128;
    int tid = threadIdx.x;
    int w = tid >> 6, l = tid & 63;
    int wr = w >> 1, wc = w & 1;
    int fr = l & 15, fk = l >> 4;
    int grow = (w & 1) * 64 + (l >> 2);
    int gcol = (w >> 1) * 32 + (l & 3) * 8;
    int srow = tid >> 1, shalf = tid & 1;
    bool fullN = (n0 + 128 <= N);

    f32x4 acc[4][4] = {};

    for (int k0 = 0; k0 < 256; k0 += 64) {
#pragma unroll
        for (int q = 0; q < 4; q++)
            GLOAD16(Aa + (long long)(m0 + grow + q * 16) * 256 + k0 + gcol,
                    &As[w * 2048 + q * 512]);
        if (fullN) {
#pragma unroll
            for (int q = 0; q < 4; q++)
                GLOAD16(Bt + (long long)(n0 + grow + q * 16) * 256 + k0 + gcol,
                        &Bs[w * 2048 + q * 512]);
        } else {
            int gn = n0 + srow;
            unsigned short* dst = &Bs[shalf * 4096 + srow * 32];
#pragma unroll
            for (int i = 0; i < 32; i++) {
                int gk = k0 + shalf * 32 + i;
                dst[i] = (gn < N) ? Bt[(long long)gn * 256 + gk] : (unsigned short)0;
            }
        }
        __syncthreads();
#pragma unroll
        for (int s = 0; s < 2; s++) {
            bf16x8 a[4], b[4];
#pragma unroll
            for (int i = 0; i < 4; i++) {
                a[i] = *(const bf16x8*)&As[s * 4096 + (wr * 64 + i * 16 + fr) * 32 + fk * 8];
                b[i] = *(const bf16x8*)&Bs[s * 4096 + (wc * 64 + i * 16 + fr) * 32 + fk * 8];
            }
#pragma unroll
            for (int i = 0; i < 4; i++)
#pragma unroll
                for (int j = 0; j < 4; j++)
                    acc[i][j] = __builtin_amdgcn_mfma_f32_16x16x32_bf16(a[i], b[j], acc[i][j], 0, 0, 0);
        }
        __syncthreads();
    }

#pragma unroll
    for (int i = 0; i < 4; i++) {
        int gr0 = m0 + wr * 64 + i * 16 + fk * 4;
#pragma unroll
        for (int j = 0; j < 4; j++) {
            int gc = n0 + wc * 64 + j * 16 + fr;
            if (gc >= N) continue;
#pragma unroll
            for (int r = 0; r < 4; r++) {
                int gr = gr0 + r;
                float v = acc[i][j][r];
                if (gc < 512) Zout[(long long)gr * 512 + gc] = f2bf(v);
                else XBCout[(long long)gr * XBCLD + (gc - 512)] = v;
            }
        }
    }
}

// ---------------- convbc v2: 25-row chunks, LDS window ----------------
__global__ __launch_bounds__(256) void convbc2_kernel(
    const float* __restrict__ XBC, const float* __restrict__ conv_w,
    const float* __restrict__ conv_b, const float* __restrict__ dt_bias,
    const float* __restrict__ A_log,
    float* __restrict__ BCb, float* __restrict__ DTb, float* __restrict__ DAb,
    float* __restrict__ BCF)
{
    __shared__ float swin[28][128];
    __shared__ float sv[25][128];
    int tid = threadIdx.x;
    int bid = blockIdx.x;
    int b = bid >> 3, c = bid & 7;
    int t0 = c * 25;
    long long rowb = (long long)b * SEQ;
    for (int i = tid; i < 28 * 32; i += 256) {
        int r = i >> 5, q = i & 31;
        int t = t0 - 3 + r;
        float4 v = (t >= 0) ? ((const float4*)(XBC + (rowb + t) * XBCLD + 512))[q]
                            : (float4){0.f, 0.f, 0.f, 0.f};
        ((float4*)&swin[r][0])[q] = v;
    }
    for (int i = tid; i < 25 * 32; i += 256) {
        int r = i >> 5, h = i & 31;
        long long row = rowb + t0 + r;
        float draw = XBC[row * XBCLD + 640 + h] + dt_bias[h];
        float dtv = (draw > 20.f) ? draw : log1pf(__expf(draw));
        DTb[row * NH + h] = dtv;
        DAb[row * NH + h] = __expf(-__expf(A_log[h]) * dtv);
    }
    __syncthreads();
    for (int i = tid; i < 25 * 128; i += 256) {
        int r = i >> 7, ch = i & 127;
        int gch = 512 + ch;
        float acc = conv_b[gch];
#pragma unroll
        for (int k = 0; k < 4; k++)
            acc = fmaf(conv_w[gch * 4 + k], swin[r + k][ch], acc);
        float v = acc * __builtin_amdgcn_rcpf(1.f + __expf(-acc));
        BCb[(rowb + t0 + r) * 128 + ch] = v;
        sv[r][ch] = v;
    }
    __syncthreads();
    int wv = tid >> 6, lane = tid & 63;
    for (int r = wv; r < 25; r += 4) {
        float prod = sv[r][lane] * sv[r][64 + lane];
#pragma unroll
        for (int m = 1; m < 64; m <<= 1) prod += __shfl_xor(prod, m);
        if (lane == 0) BCF[rowb + t0 + r] = prod;
    }
}

// ---------------- selective scan v7b: old-state dot ----------------
__device__ __forceinline__ void sstep2(
    float raw, float dtv, float da, float bc,
    const float4& qb0, const float4& qb1, const float4& qb2, const float4& qb3,
    const float4& qc0, const float4& qc1, const float4& qc2, const float4& qc3,
    float cw0, float cw1, float cw2, float cw3, float cb, float ds,
    float* st, float& w0, float& w1, float& w2,
    int lane, float* __restrict__ yaddr)
{
    float cvv = cb + cw0 * w0 + cw1 * w1 + cw2 * w2 + cw3 * raw;
    float xhv = cvv * __builtin_amdgcn_rcpf(1.f + __expf(-cvv));
    w0 = w1; w1 = w2; w2 = raw;
    float xv = dtv * xhv;
    float p0 = st[0]  * qc0.x;
    float p1 = st[1]  * qc0.y;
    float p2 = st[2]  * qc0.z;
    float p3 = st[3]  * qc0.w;
    p0 = fmaf(st[4],  qc1.x, p0);
    p1 = fmaf(st[5],  qc1.y, p1);
    p2 = fmaf(st[6],  qc1.z, p2);
    p3 = fmaf(st[7],  qc1.w, p3);
    p0 = fmaf(st[8],  qc2.x, p0);
    p1 = fmaf(st[9],  qc2.y, p1);
    p2 = fmaf(st[10], qc2.z, p2);
    p3 = fmaf(st[11], qc2.w, p3);
    p0 = fmaf(st[12], qc3.x, p0);
    p1 = fmaf(st[13], qc3.y, p1);
    p2 = fmaf(st[14], qc3.z, p2);
    p3 = fmaf(st[15], qc3.w, p3);
    st[0]  = fmaf(da, st[0],  xv * qb0.x);
    st[1]  = fmaf(da, st[1],  xv * qb0.y);
    st[2]  = fmaf(da, st[2],  xv * qb0.z);
    st[3]  = fmaf(da, st[3],  xv * qb0.w);
    st[4]  = fmaf(da, st[4],  xv * qb1.x);
    st[5]  = fmaf(da, st[5],  xv * qb1.y);
    st[6]  = fmaf(da, st[6],  xv * qb1.z);
    st[7]  = fmaf(da, st[7],  xv * qb1.w);
    st[8]  = fmaf(da, st[8],  xv * qb2.x);
    st[9]  = fmaf(da, st[9],  xv * qb2.y);
    st[10] = fmaf(da, st[10], xv * qb2.z);
    st[11] = fmaf(da, st[11], xv * qb2.w);
    st[12] = fmaf(da, st[12], xv * qb3.x);
    st[13] = fmaf(da, st[13], xv * qb3.y);
    st[14] = fmaf(da, st[14], xv * qb3.z);
    st[15] = fmaf(da, st[15], xv * qb3.w);
    float part = (p0 + p1) + (p2 + p3);
    part += __shfl_xor(part, 16);
    part += __shfl_xor(part, 32);
    if (lane < HD) *yaddr = fmaf(da, part, fmaf(xv, bc, ds * xhv));
}

__global__ __launch_bounds__(256) void scan7b_kernel(
    const float* __restrict__ DTb, const float* __restrict__ DAb,
    float* __restrict__ XBC, const float* __restrict__ BCb,
    const float* __restrict__ Dsk,
    const float* __restrict__ conv_w, const float* __restrict__ conv_b,
    const float* __restrict__ BCF)
{
    __shared__ float sbc[2][TC][128];
    __shared__ unsigned short sx[2][TC][128];
    __shared__ float sdt[2][TC][8];
    __shared__ float sda[2][TC][8];
    __shared__ float sbcf[2][TC];
    int tid = threadIdx.x;
    int wv = tid >> 6, lane = tid & 63;
    int bid = blockIdx.x;
    int b = bid >> 2, hq = (bid & 3) * 8;
    long long rowb = (long long)b * SEQ;

    for (int i = tid; i < TC * 32; i += 256) {
        int r = i >> 5, c = i & 31;
        ((float4*)&sbc[0][r][0])[c] = ((const float4*)(BCb + (rowb + r) * 128))[c];
    }
    for (int i = tid; i < TC * 64; i += 256) {
        int r = i >> 6, c2 = i & 63;
        float2 v = *(const float2*)(XBC + (rowb + r) * XBCLD + hq * 16 + (c2 << 1));
        *(unsigned*)&sx[0][r][c2 << 1] = (unsigned)f2bf(v.x) | ((unsigned)f2bf(v.y) << 16);
    }
    for (int i = tid; i < TC * 8; i += 256) {
        int t = i >> 3, j = i & 7;
        sdt[0][t][j] = DTb[(rowb + t) * NH + hq + j];
        sda[0][t][j] = DAb[(rowb + t) * NH + hq + j];
    }
    if (tid < TC) sbcf[0][tid] = BCF[rowb + tid];
    __syncthreads();

    int p = lane & 15, g = lane >> 4;
    int hA = hq + wv, hB = hq + 4 + wv;
    int chA = hA * HD + p, chB = hB * HD + p;
    float cwA0 = conv_w[chA * 4 + 0], cwA1 = conv_w[chA * 4 + 1];
    float cwA2 = conv_w[chA * 4 + 2], cwA3 = conv_w[chA * 4 + 3];
    float cbA = conv_b[chA];
    float cwB0 = conv_w[chB * 4 + 0], cwB1 = conv_w[chB * 4 + 1];
    float cwB2 = conv_w[chB * 4 + 2], cwB3 = conv_w[chB * 4 + 3];
    float cbB = conv_b[chB];
    float dsA = Dsk[hA], dsB = Dsk[hB];
    int xcA = wv * 16 + p, xcB = (4 + wv) * 16 + p;
    float* ypA = XBC + rowb * XBCLD + hA * HD + p;
    float* ypB = XBC + rowb * XBCLD + hB * HD + p;
    float stA[16], stB[16];
#pragma unroll
    for (int r = 0; r < 16; r++) { stA[r] = 0.f; stB[r] = 0.f; }
    float wA0 = 0.f, wA1 = 0.f, wA2 = 0.f;
    float wB0 = 0.f, wB1 = 0.f, wB2 = 0.f;

    for (int c = 0; c < NCH; c++) {
        int cur = c & 1;
        if (c + 1 < NCH) {
            int nb = cur ^ 1;
            long long tb = rowb + (c + 1) * TC;
            for (int i = tid; i < TC * 32; i += 256) {
                int r = i >> 5, cc = i & 31;
                ((float4*)&sbc[nb][r][0])[cc] = ((const float4*)(BCb + (tb + r) * 128))[cc];
            }
            for (int i = tid; i < TC * 64; i += 256) {
                int r = i >> 6, c2 = i & 63;
                float2 v = *(const float2*)(XBC + (tb + r) * XBCLD + hq * 16 + (c2 << 1));
                *(unsigned*)&sx[nb][r][c2 << 1] = (unsigned)f2bf(v.x) | ((unsigned)f2bf(v.y) << 16);
            }
            for (int i = tid; i < TC * 8; i += 256) {
                int t = i >> 3, j = i & 7;
                sdt[nb][t][j] = DTb[(tb + t) * NH + hq + j];
                sda[nb][t][j] = DAb[(tb + t) * NH + hq + j];
            }
            if (tid < TC) sbcf[nb][tid] = BCF[tb + tid];
        }
        int tbase = c * TC;
        for (int t = 0; t < TC; t++) {
            int gt = tbase + t;
            const float4* qb = (const float4*)&sbc[cur][t][g * 16];
            const float4* qc = (const float4*)&sbc[cur][t][64 + g * 16];
            float4 qb0 = qb[0], qb1 = qb[1], qb2 = qb[2], qb3 = qb[3];
            float4 qc0 = qc[0], qc1 = qc[1], qc2 = qc[2], qc3 = qc[3];
            float rawA = bf2f(sx[cur][t][xcA]);
            float rawB = bf2f(sx[cur][t][xcB]);
            float bc = sbcf[cur][t];
            sstep2(rawA, sdt[cur][t][wv], sda[cur][t][wv], bc,
                   qb0, qb1, qb2, qb3, qc0, qc1, qc2, qc3,
                   cwA0, cwA1, cwA2, cwA3, cbA, dsA, stA, wA0, wA1, wA2,
                   lane, ypA + (long long)gt * XBCLD);
            sstep2(rawB, sdt[cur][t][4 + wv], sda[cur][t][4 + wv], bc,
                   qb0, qb1, qb2, qb3, qc0, qc1, qc2, qc3,
                   cwB0, cwB1, cwB2, cwB3, cbB, dsB, stB, wB0, wB1, wB2,
                   lane, ypB + (long long)gt * XBCLD);
        }
        __syncthreads();
    }
}

// ---------------- gate: G = rmsnorm(y * silu(z)) * w  (bf16 out, in-place) ----------------
__global__ __launch_bounds__(256) void gate_kernel(
    float* __restrict__ XBC, const unsigned short* __restrict__ Zbf,
    const float* __restrict__ rms_w)
{
    int row = blockIdx.x * 4 + (threadIdx.x >> 6);
    int lane = threadIdx.x & 63;
    float* yrow = XBC + (long long)row * XBCLD + lane * 8;
    const unsigned short* zrow = Zbf + (long long)row * 512 + lane * 8;
    float4 y0 = ((const float4*)yrow)[0];
    float4 y1 = ((const float4*)yrow)[1];
    uint4 zq = ((const uint4*)zrow)[0];
    float yv[8] = { y0.x, y0.y, y0.z, y0.w, y1.x, y1.y, y1.z, y1.w };
    float zv[8];
    zv[0] = bf2f((unsigned short)(zq.x & 0xFFFF)); zv[1] = bf2f((unsigned short)(zq.x >> 16));
    zv[2] = bf2f((unsigned short)(zq.y & 0xFFFF)); zv[3] = bf2f((unsigned short)(zq.y >> 16));
    zv[4] = bf2f((unsigned short)(zq.z & 0xFFFF)); zv[5] = bf2f((unsigned short)(zq.z >> 16));
    zv[6] = bf2f((unsigned short)(zq.w & 0xFFFF)); zv[7] = bf2f((unsigned short)(zq.w >> 16));
    float a[8]; float ss = 0.f;
#pragma unroll
    for (int i = 0; i < 8; i++) {
        float z = zv[i];
        a[i] = yv[i] * (z * __builtin_amdgcn_rcpf(1.f + __expf(-z)));
        ss = fmaf(a[i], a[i], ss);
    }
#pragma unroll
    for (int m = 1; m < 64; m <<= 1) ss += __shfl_xor(ss, m);
    float sc = rsqrtf(ss * (1.f / 512.f) + 1e-5f);
    const float* rw = rms_w + lane * 8;
    float4 r0 = ((const float4*)rw)[0];
    float4 r1 = ((const float4*)rw)[1];
    float rv[8] = { r0.x, r0.y, r0.z, r0.w, r1.x, r1.y, r1.z, r1.w };
    uint4 o;
    o.x = (unsigned)f2bf(a[0] * sc * rv[0]) | ((unsigned)f2bf(a[1] * sc * rv[1]) << 16);
    o.y = (unsigned)f2bf(a[2] * sc * rv[2]) | ((unsigned)f2bf(a[3] * sc * rv[3]) << 16);
    o.z = (unsigned)f2bf(a[4] * sc * rv[4]) | ((unsigned)f2bf(a[5] * sc * rv[5]) << 16);
    o.w = (unsigned)f2bf(a[6] * sc * rv[6]) | ((unsigned)f2bf(a[7] * sc * rv[7]) << 16);
    unsigned short* grow = (unsigned short*)(XBC + (long long)row * XBCLD);
    ((uint4*)grow)[lane] = o;
}

// ---------------- LayerNorm(bf16 a + bf16 b)*g+be -> f32 ----------------
__global__ void lnadd_bb_kernel(const unsigned short* __restrict__ A, const unsigned short* __restrict__ Bb,
                                const float* __restrict__ g, const float* __restrict__ be,
                                float* __restrict__ O)
{
    int row = blockIdx.x * 4 + (threadIdx.x >> 6);
    int lane = threadIdx.x & 63;
    long long base = (long long)row * DMODEL + lane * 4;
    float v[4]; float s1 = 0.f;
#pragma unroll
    for (int i = 0; i < 4; i++) { float a = bf2f(A[base + i]) + bf2f(Bb[base + i]); v[i] = a; s1 += a; }
#pragma unroll
    for (int m = 1; m < 64; m <<= 1) s1 += __shfl_xor(s1, m);
    float mean = s1 * (1.f / 256.f);
    float s2 = 0.f;
#pragma unroll
    for (int i = 0; i < 4; i++) { float d = v[i] - mean; s2 = fmaf(d, d, s2); }
#pragma unroll
    for (int m = 1; m < 64; m <<= 1) s2 += __shfl_xor(s2, m);
    float r = rsqrtf(s2 * (1.f / 256.f) + 1e-12f);
#pragma unroll
    for (int i = 0; i < 4; i++)
        O[base + i] = (v[i] - mean) * r * g[lane * 4 + i] + be[lane * 4 + i];
}

// ---------------- fused: H = alpha*LN(MO+x) + beta*LN(XI+x) -> bf16 HB ----------------
__global__ void combine2_kernel(const unsigned short* __restrict__ XI, const float* __restrict__ X,
                                const float* __restrict__ MO, unsigned short* __restrict__ HB,
                                const float* __restrict__ lg, const float* __restrict__ lb,
                                const float* __restrict__ fg, const float* __restrict__ fb,
                                const float* __restrict__ al, const float* __restrict__ bt)
{
    int row = blockIdx.x * 4 + (threadIdx.x >> 6);
    int lane = threadIdx.x & 63;
    long long base = (long long)row * DMODEL + lane * 4;
    int bb = row / SEQ, ll = row - bb * SEQ;
    long long xib = (long long)bb * 65536 + ll * 256 + lane * 4;
    float u[4], v[4]; float su = 0.f, sv = 0.f;
#pragma unroll
    for (int i = 0; i < 4; i++) {
        float xv = X[base + i];
        float a = MO[base + i] + xv;
        float b = bf2f(XI[xib + i]) + xv;
        u[i] = a; v[i] = b; su += a; sv += b;
    }
#pragma unroll
    for (int m = 1; m < 64; m <<= 1) { su += __shfl_xor(su, m); sv += __shfl_xor(sv, m); }
    float mu = su * (1.f / 256.f), mv = sv * (1.f / 256.f);
    float qu = 0.f, qv = 0.f;
#pragma unroll
    for (int i = 0; i < 4; i++) {
        float du = u[i] - mu; qu = fmaf(du, du, qu);
        float dv = v[i] - mv; qv = fmaf(dv, dv, qv);
    }
#pragma unroll
    for (int m = 1; m < 64; m <<= 1) { qu += __shfl_xor(qu, m); qv += __shfl_xor(qv, m); }
    float ru = rsqrtf(qu * (1.f / 256.f) + 1e-12f);
    float rv = rsqrtf(qv * (1.f / 256.f) + 1e-12f);
#pragma unroll
    for (int i = 0; i < 4; i++) {
        int d = lane * 4 + i;
        float h1 = (u[i] - mu) * ru * lg[d] + lb[d];
        float h2 = (v[i] - mv) * rv * fg[d] + fb[d];
        float h = al[d] * h1 + bt[d] * h2;
        HB[base + i] = f2bf(h);
    }
}

// ---------------- pointwise spectral filter on XFT[b][d][j] bf16 (ld 256) ----------------
__global__ void filt_kernel(unsigned short* __restrict__ XF, const float* __restrict__ W)
{
    long long idx = (long long)blockIdx.x * 256 + threadIdx.x;
    if (idx >= (long long)BATCHN * DMODEL * NF) return;
    int f = (int)(idx % NF);
    int d = (int)((idx / NF) % DMODEL);
    int b = (int)(idx / ((long long)NF * DMODEL));
    long long base = ((long long)b * DMODEL + d) * 256;
    float re = bf2f(XF[base + f]);
    float im = bf2f(XF[base + 101 + f]);
    float wr = W[((long long)f * DMODEL + d) * 2];
    float wi = W[((long long)f * DMODEL + d) * 2 + 1];
    XF[base + f]       = f2bf(re * wr - im * wi);
    XF[base + 101 + f] = f2bf(re * wi + im * wr);
}

extern "C" void kernel_launch(void* const* d_in, const int* in_sizes, int n_in,
                              void* d_out, int out_size, void* d_ws, size_t ws_size,
                              hipStream_t stream)
{
    const float* x          = (const float*)d_in[0];
    const float* in_proj_w  = (const float*)d_in[1];
    const float* conv_w     = (const float*)d_in[2];
    const float* conv_b     = (const float*)d_in[3];
    const float* dt_bias    = (const float*)d_in[4];
    const float* A_log      = (const float*)d_in[5];
    const float* D_skip     = (const float*)d_in[6];
    const float* rms_w      = (const float*)d_in[7];
    const float* out_proj_w = (const float*)d_in[8];
    const float* ln_g       = (const float*)d_in[9];
    const float* ln_b       = (const float*)d_in[10];
    const float* filt_w     = (const float*)d_in[11];
    const float* filt_ln_g  = (const float*)d_in[12];
    const float* filt_ln_b  = (const float*)d_in[13];
    const float* alpha      = (const float*)d_in[14];
    const float* beta       = (const float*)d_in[15];
    const float* ffn_w1     = (const float*)d_in[16];
    const float* ffn_b1     = (const float*)d_in[17];
    const float* ffn_w2     = (const float*)d_in[18];
    const float* ffn_b2     = (const float*)d_in[19];
    const float* ffn_ln_g   = (const float*)d_in[20];
    const float* ffn_ln_b   = (const float*)d_in[21];
    float* out = (float*)d_out;
    float* ws = (float*)d_ws;

    // weights arena [81920 .. XBASE)
    unsigned short* WP    = (unsigned short*)(ws + 81920);
    unsigned short* wTall = WP;                  // 1184*256
    unsigned short* opwT  = wTall + 1184 * 256;  // 256*512
    unsigned short* w1T   = opwT + 256 * 512;    // 1024*256
    unsigned short* w2T   = w1T + 1024 * 256;    // 256*1024
    unsigned short* EFbf  = w2T + 256 * 1024;    // 256*200
    unsigned short* EIbf  = EFbf + 256 * SEQ;    // 256*256
    float* XBC = ws + XBASE;                     // BL*672 f32 arena
    float* BCb = XBC + (long long)BL * XBCLD;    // BL*128
    float* DTb = BCb + (long long)BL * 128;      // BL*32
    float* DAb = DTb + (long long)BL * NH;       // BL*32
    float* MO  = DAb + (long long)BL * NH;       // BL*256 (h1 pre-LN)
    float* BCF = MO + (long long)BL * DMODEL;    // BL  (b·c per row)
    unsigned short* Zbf = (unsigned short*)MO;   // BL*512 bf16, lifetime [proj..gate]
    // BCb region reuse:
    unsigned short* xbf  = (unsigned short*)BCb; // bf16 x, lifetime [setup..proj]
    unsigned short* xTbf = (unsigned short*)BCb; // lifetime [xT..FFT fwd]
    unsigned short* MObf = (unsigned short*)BCb; // bf16 H, lifetime [combine2..lnadd_bb]
    // XBC arena reuse:
    unsigned short* Gbf = (unsigned short*)XBC;              // bf16 G in place, ld 1344
    unsigned short* XFT = (unsigned short*)XBC;              // 256*256*256 bf16
    unsigned short* XI  = (unsigned short*)(XBC + XIOFF);    // 256*65536 bf16
    unsigned short* HID = (unsigned short*)XBC;              // BL*1024 bf16 (post-combine2)
    unsigned short* FFO = (unsigned short*)(XBC + 26500000); // BL*256 bf16

    // 1. DFT matrices + merged setup (packs + x->bf16)
    init_dft_kernel<<<dim3((256 * SEQ + 256 * 256 + 255) / 256), dim3(256), 0, stream>>>(EFbf, EIbf);
    setup_kernel<<<dim3((S0 + S1 + S2 + S3 + S4) / 256), dim3(256), 0, stream>>>(
        in_proj_w, out_proj_w, ffn_w1, ffn_w2, x, wTall, opwT, w1T, w2T, xbf);

    // 2. merged projection: xbf[BL,256] @ wTall^T -> Zbf (cols<512) + XBC (cols>=512)
    mgemm_proj<<<dim3(10, BL / 128), dim3(256), 0, stream>>>(xbf, wTall, XBC, Zbf);

    // 3. conv+silu B/C; dt -> DT/DA; bc -> BCF (clobbers xbf)
    convbc2_kernel<<<dim3(BATCHN * 8), dim3(256), 0, stream>>>(XBC, conv_w, conv_b, dt_bias,
                                                               A_log, BCb, DTb, DAb, BCF);

    // 4. scan v7b, y in place f32
    scan7b_kernel<<<dim3(BATCHN * 4), dim3(256), 0, stream>>>(DTb, DAb, XBC, BCb, D_skip,
                                                              conv_w, conv_b, BCF);

    // 4.5 x transpose -> xTbf (BCb dead after scan)
    xT_kernel<<<dim3(7, 8, BATCHN), dim3(256), 0, stream>>>(x, xTbf);

    // 5. gate -> Gbf bf16 in place
    gate_kernel<<<dim3(BL / 4), dim3(256), 0, stream>>>(XBC, Zbf, rms_w);

    // 6. out_proj: Gbf[BL,512](ld 1344) @ opwT^T -> MO f32 (Zbf dead)
    mgemm_kernel<0,0><<<dim3(2, BL / 128, 1), dim3(256), 0, stream>>>(
        Gbf, opwT, MO, nullptr, BL, 256, 512, 1344, 512, 256, 0, 0, 0);

    // 7. FFT fwd: XFT[b][256][256] = xTbf[b][256,200] @ EFbf[256,200]^T, bf16 (ld 256)
    mgemm_kernel<0,1><<<dim3(2, 2, BATCHN), dim3(256), 0, stream>>>(
        xTbf, EFbf, XFT, nullptr, 256, 256, SEQ, SEQ, SEQ, 256,
        (long long)DMODEL * SEQ, 0, 65536);

    // 8. spectral filter in place
    filt_kernel<<<dim3((BATCHN * DMODEL * NF + 255) / 256), dim3(256), 0, stream>>>(XFT, filt_w);

    // 9. FFT inv: XI[b][256][256] = EIbf[256,256] @ XFT[b]^T, bf16 out (batch stride 65536)
    mgemm_kernel<0,1><<<dim3(2, 2, BATCHN), dim3(256), 0, stream>>>(
        EIbf, XFT, XI, nullptr, 256, 256, 256, 256, 256, 256,
        0, 65536, 65536);

    // 10. fused combine -> bf16 H only (MObf; xTbf dead)
    combine2_kernel<<<dim3(BL / 4), dim3(256), 0, stream>>>(XI, x, MO, MObf,
                                                            ln_g, ln_b, filt_ln_g, filt_ln_b,
                                                            alpha, beta);

    // 11. FFN1: MObf[BL,256] @ w1T^T + b1, GELU -> HID bf16 (XI dead)
    mgemm_kernel<1,1><<<dim3(8, BL / 128, 1), dim3(256), 0, stream>>>(
        MObf, w1T, HID, ffn_b1, BL, 1024, 256, 256, 256, 1024, 0, 0, 0);

    // 12. FFN2: HID[BL,1024] @ w2T^T + b2 -> FFO bf16
    mgemm_kernel<0,1><<<dim3(2, BL / 128, 1), dim3(256), 0, stream>>>(
        HID, w2T, FFO, ffn_b2, BL, 256, 1024, 1024, 1024, 256, 0, 0, 0);

    // 13. out = LN(FFO + H)
    lnadd_bb_kernel<<<dim3(BL / 4), dim3(256), 0, stream>>>(FFO, MObf, ffn_ln_g, ffn_ln_b, out);
}

// Round 15
// 786.930 us; speedup vs baseline: 1.0223x; 1.0223x over previous
//
#include <hip/hip_runtime.h>
#include <math.h>

#define BATCHN 256
#define SEQ 200
#define DMODEL 256
#define DINNER 512
#define NH 32
#define HD 16
#define DSTATE 64
#define DINPROJ 1184
#define XBCLD 672
#define BL (BATCHN*SEQ)   // 51200
#define NF 101
#define XBASE 655360
#define TC 20
#define NCH 10
#define XIOFF 8500000     // f32 offset of XI within XBC arena

typedef __attribute__((ext_vector_type(8))) short bf16x8;
typedef __attribute__((ext_vector_type(4))) float f32x4;

__device__ inline unsigned short f2bf(float f) {
    union { float f; unsigned u; } v; v.f = f;
    unsigned r = v.u + 0x7FFFu + ((v.u >> 16) & 1u);
    return (unsigned short)(r >> 16);
}
__device__ inline float bf2f(unsigned short h) {
    union { unsigned u; float f; } v; v.u = ((unsigned)h) << 16;
    return v.f;
}

#define GLOAD16(src, dst) __builtin_amdgcn_global_load_lds( \
    (const __attribute__((address_space(1))) void*)(src),   \
    (__attribute__((address_space(3))) void*)(dst), 16, 0, 0)

// ---------------- DFT matrices (bf16, padded to 256) ----------------
__global__ void init_dft_kernel(unsigned short* __restrict__ EF, unsigned short* __restrict__ EI)
{
    const float ang = 6.28318530717958647692f / 200.0f;
    int idx = blockIdx.x * 256 + threadIdx.x;
    if (idx < 256 * SEQ) {
        int f = idx / SEQ, t = idx - f * SEQ;
        float v;
        if (f <= 100) { int ph = (f * t) % 200; v = cosf(ang * (float)ph); }
        else if (f <= 201) { int ff = f - 101; int ph = (ff * t) % 200; v = -sinf(ang * (float)ph); }
        else v = 0.f;
        EF[idx] = f2bf(v);
    } else if (idx < 256 * SEQ + 256 * 256) {
        int j2 = idx - 256 * SEQ;
        int t = j2 >> 8, j = j2 & 255;
        float v;
        if (t >= 200) v = 0.f;
        else if (j == 0) v = 1.0f / 200.0f;
        else if (j == 100) v = ((t & 1) ? -1.0f : 1.0f) / 200.0f;
        else if (j < 100) { int ph = (j * t) % 200; v = 2.0f * cosf(ang * (float)ph) / 200.0f; }
        else if (j >= 202 || j == 101 || j == 201) v = 0.0f;
        else { int f = j - 101; int ph = (f * t) % 200; v = -2.0f * sinf(ang * (float)ph) / 200.0f; }
        EI[j2] = f2bf(v);
    }
}

// ---------------- merged setup: weight packs + x->bf16 ----------------
#define S0 303104   // wTall 1184*256
#define S1 131072   // opwT 256*512
#define S2 262144   // w1T 1024*256
#define S3 262144   // w2T 256*1024
#define S4 1638400  // f2bf groups of 8
__global__ void setup_kernel(const float* __restrict__ ipw, const float* __restrict__ opw,
                             const float* __restrict__ w1, const float* __restrict__ w2,
                             const float* __restrict__ X,
                             unsigned short* __restrict__ wTall, unsigned short* __restrict__ opwT,
                             unsigned short* __restrict__ w1T, unsigned short* __restrict__ w2T,
                             unsigned short* __restrict__ xbf)
{
    long long idx = (long long)blockIdx.x * 256 + threadIdx.x;
    if (idx < S0) { int n = (int)(idx / 256), k = (int)(idx % 256);
        wTall[idx] = f2bf(ipw[(long long)k * DINPROJ + n]); return; }
    idx -= S0;
    if (idx < S1) { int n = (int)(idx / 512), k = (int)(idx % 512);
        opwT[idx] = f2bf(opw[(long long)k * 256 + n]); return; }
    idx -= S1;
    if (idx < S2) { int n = (int)(idx / 256), k = (int)(idx % 256);
        w1T[idx] = f2bf(w1[(long long)k * 1024 + n]); return; }
    idx -= S2;
    if (idx < S3) { int n = (int)(idx / 1024), k = (int)(idx % 1024);
        w2T[idx] = f2bf(w2[(long long)k * 256 + n]); return; }
    idx -= S3;
    if (idx < S4) {
        long long i = idx * 8;
        float4 a = ((const float4*)(X + i))[0];
        float4 b = ((const float4*)(X + i))[1];
        uint4 o;
        o.x = (unsigned)f2bf(a.x) | ((unsigned)f2bf(a.y) << 16);
        o.y = (unsigned)f2bf(a.z) | ((unsigned)f2bf(a.w) << 16);
        o.z = (unsigned)f2bf(b.x) | ((unsigned)f2bf(b.y) << 16);
        o.w = (unsigned)f2bf(b.z) | ((unsigned)f2bf(b.w) << 16);
        *(uint4*)(xbf + i) = o;
    }
}

// ---------------- x transpose: xT[b][d][t] = bf16(x[b][t][d]) ----------------
__global__ void xT_kernel(const float* __restrict__ X, unsigned short* __restrict__ XT)
{
    __shared__ float tile[32][33];
    int b = blockIdx.z, t0 = blockIdx.x * 32, d0 = blockIdx.y * 32;
    int tx = threadIdx.x & 31, ty = threadIdx.x >> 5;
    const float* xb = X + (long long)b * SEQ * DMODEL;
#pragma unroll
    for (int i = 0; i < 4; i++) {
        int t = t0 + ty + i * 8;
        tile[ty + i * 8][tx] = (t < SEQ) ? xb[(long long)t * DMODEL + d0 + tx] : 0.f;
    }
    __syncthreads();
    unsigned short* xtb = XT + (long long)b * DMODEL * SEQ;
#pragma unroll
    for (int i = 0; i < 4; i++) {
        int d = d0 + ty + i * 8;
        int t = t0 + tx;
        if (t < SEQ) xtb[(long long)d * SEQ + t] = f2bf(tile[tx][ty + i * 8]);
    }
}

// ---------------- bf16 MFMA GEMM: BK=32, global_load_lds, linear LDS ----------------
template<int ACT, int CBF>
__global__ __launch_bounds__(256) void mgemm_kernel(
    const unsigned short* __restrict__ Ab, const unsigned short* __restrict__ BTp,
    void* __restrict__ Cp, const float* __restrict__ bias,
    int M, int N, int K, int lda, int ldbt, int ldc,
    long long sA, long long sBT, long long sC)
{
    __shared__ unsigned short As[128 * 32];
    __shared__ unsigned short Bs[128 * 32];
    const unsigned short* Aa = Ab + (long long)blockIdx.z * sA;
    const unsigned short* Bt = BTp + (long long)blockIdx.z * sBT;
    float* Cf = (float*)Cp + (CBF ? 0 : (long long)blockIdx.z * sC);
    unsigned short* Cb = (unsigned short*)Cp + (CBF ? (long long)blockIdx.z * sC : 0);

    int m0 = blockIdx.y * 128, n0 = blockIdx.x * 128;
    int tid = threadIdx.x;
    int srow = tid >> 1, skb = (tid & 1) * 16;
    int w = tid >> 6, l = tid & 63;
    int wr = w >> 1, wc = w & 1;
    int fr = l & 15, fk = l >> 4;
    int glr = (w << 4) + (l >> 2);
    int glc = (l & 3) << 3;
    bool fullM = (m0 + 128 <= M);
    bool fullN = (n0 + 128 <= N);

    f32x4 acc[4][4] = {};

    for (int k0 = 0; k0 < K; k0 += 32) {
        bool kedge = (k0 + 32 > K);
        if (fullM && !kedge) {
            GLOAD16(Aa + (long long)(m0 + glr) * lda + k0 + glc,      &As[w << 9]);
            GLOAD16(Aa + (long long)(m0 + 64 + glr) * lda + k0 + glc, &As[2048 + (w << 9)]);
        } else {
            int gm = m0 + srow;
            unsigned short* dst = &As[srow * 32 + skb];
#pragma unroll
            for (int i = 0; i < 16; i++) {
                int gk = k0 + skb + i;
                dst[i] = (gm < M && gk < K) ? Aa[(long long)gm * lda + gk] : (unsigned short)0;
            }
        }
        if (fullN && !kedge) {
            GLOAD16(Bt + (long long)(n0 + glr) * ldbt + k0 + glc,      &Bs[w << 9]);
            GLOAD16(Bt + (long long)(n0 + 64 + glr) * ldbt + k0 + glc, &Bs[2048 + (w << 9)]);
        } else {
            int gn = n0 + srow;
            unsigned short* dst = &Bs[srow * 32 + skb];
#pragma unroll
            for (int i = 0; i < 16; i++) {
                int gk = k0 + skb + i;
                dst[i] = (gn < N && gk < K) ? Bt[(long long)gn * ldbt + gk] : (unsigned short)0;
            }
        }
        __syncthreads();
        bf16x8 a[4], b[4];
#pragma unroll
        for (int i = 0; i < 4; i++) {
            a[i] = *(const bf16x8*)&As[(wr * 64 + i * 16 + fr) * 32 + fk * 8];
            b[i] = *(const bf16x8*)&Bs[(wc * 64 + i * 16 + fr) * 32 + fk * 8];
        }
#pragma unroll
        for (int i = 0; i < 4; i++)
#pragma unroll
            for (int j = 0; j < 4; j++)
                acc[i][j] = __builtin_amdgcn_mfma_f32_16x16x32_bf16(a[i], b[j], acc[i][j], 0, 0, 0);
        __syncthreads();
    }

#pragma unroll
    for (int i = 0; i < 4; i++) {
        int gr0 = m0 + wr * 64 + i * 16 + fk * 4;
#pragma unroll
        for (int j = 0; j < 4; j++) {
            int gc = n0 + wc * 64 + j * 16 + fr;
            if (gc >= N) continue;
            float bv = bias ? bias[gc] : 0.f;
#pragma unroll
            for (int r = 0; r < 4; r++) {
                int gr = gr0 + r;
                if (gr >= M) continue;
                float v = acc[i][j][r] + bv;
                if (ACT == 1) v = 0.5f * v * (1.f + erff(v * 0.70710678118654752f));
                long long ci = (long long)gr * ldc + gc;
                if (CBF) Cb[ci] = f2bf(v);
                else Cf[ci] = v;
            }
        }
    }
}

// ---------------- merged projection GEMM: N=1184; cols<512 -> Zbf, >=512 -> XBC ----------------
__global__ __launch_bounds__(256) void mgemm_proj(
    const unsigned short* __restrict__ Aa, const unsigned short* __restrict__ Bt,
    float* __restrict__ XBCout, unsigned short* __restrict__ Zout)
{
    __shared__ unsigned short As[128 * 32];
    __shared__ unsigned short Bs[128 * 32];
    const int N = DINPROJ;
    int m0 = blockIdx.y * 128, n0 = blockIdx.x * 128;
    int tid = threadIdx.x;
    int srow = tid >> 1, skb = (tid & 1) * 16;
    int w = tid >> 6, l = tid & 63;
    int wr = w >> 1, wc = w & 1;
    int fr = l & 15, fk = l >> 4;
    int glr = (w << 4) + (l >> 2);
    int glc = (l & 3) << 3;
    bool fullN = (n0 + 128 <= N);

    f32x4 acc[4][4] = {};

    for (int k0 = 0; k0 < 256; k0 += 32) {
        GLOAD16(Aa + (long long)(m0 + glr) * 256 + k0 + glc,      &As[w << 9]);
        GLOAD16(Aa + (long long)(m0 + 64 + glr) * 256 + k0 + glc, &As[2048 + (w << 9)]);
        if (fullN) {
            GLOAD16(Bt + (long long)(n0 + glr) * 256 + k0 + glc,      &Bs[w << 9]);
            GLOAD16(Bt + (long long)(n0 + 64 + glr) * 256 + k0 + glc, &Bs[2048 + (w << 9)]);
        } else {
            int gn = n0 + srow;
            unsigned short* dst = &Bs[srow * 32 + skb];
#pragma unroll
            for (int i = 0; i < 16; i++)
                dst[i] = (gn < N) ? Bt[(long long)gn * 256 + k0 + skb + i] : (unsigned short)0;
        }
        __syncthreads();
        bf16x8 a[4], b[4];
#pragma unroll
        for (int i = 0; i < 4; i++) {
            a[i] = *(const bf16x8*)&As[(wr * 64 + i * 16 + fr) * 32 + fk * 8];
            b[i] = *(const bf16x8*)&Bs[(wc * 64 + i * 16 + fr) * 32 + fk * 8];
        }
#pragma unroll
        for (int i = 0; i < 4; i++)
#pragma unroll
            for (int j = 0; j < 4; j++)
                acc[i][j] = __builtin_amdgcn_mfma_f32_16x16x32_bf16(a[i], b[j], acc[i][j], 0, 0, 0);
        __syncthreads();
    }

#pragma unroll
    for (int i = 0; i < 4; i++) {
        int gr0 = m0 + wr * 64 + i * 16 + fk * 4;
#pragma unroll
        for (int j = 0; j < 4; j++) {
            int gc = n0 + wc * 64 + j * 16 + fr;
            if (gc >= N) continue;
#pragma unroll
            for (int r = 0; r < 4; r++) {
                int gr = gr0 + r;
                float v = acc[i][j][r];
                if (gc < 512) Zout[(long long)gr * 512 + gc] = f2bf(v);
                else XBCout[(long long)gr * XBCLD + (gc - 512)] = v;
            }
        }
    }
}

// ---------------- convbc v2: 25-row chunks, LDS window ----------------
__global__ __launch_bounds__(256) void convbc2_kernel(
    const float* __restrict__ XBC, const float* __restrict__ conv_w,
    const float* __restrict__ conv_b, const float* __restrict__ dt_bias,
    const float* __restrict__ A_log,
    float* __restrict__ BCb, float* __restrict__ DTb, float* __restrict__ DAb,
    float* __restrict__ BCF)
{
    __shared__ float swin[28][128];
    __shared__ float sv[25][128];
    int tid = threadIdx.x;
    int bid = blockIdx.x;
    int b = bid >> 3, c = bid & 7;
    int t0 = c * 25;
    long long rowb = (long long)b * SEQ;
    for (int i = tid; i < 28 * 32; i += 256) {
        int r = i >> 5, q = i & 31;
        int t = t0 - 3 + r;
        float4 v = (t >= 0) ? ((const float4*)(XBC + (rowb + t) * XBCLD + 512))[q]
                            : (float4){0.f, 0.f, 0.f, 0.f};
        ((float4*)&swin[r][0])[q] = v;
    }
    for (int i = tid; i < 25 * 32; i += 256) {
        int r = i >> 5, h = i & 31;
        long long row = rowb + t0 + r;
        float draw = XBC[row * XBCLD + 640 + h] + dt_bias[h];
        float dtv = (draw > 20.f) ? draw : log1pf(__expf(draw));
        DTb[row * NH + h] = dtv;
        DAb[row * NH + h] = __expf(-__expf(A_log[h]) * dtv);
    }
    __syncthreads();
    for (int i = tid; i < 25 * 128; i += 256) {
        int r = i >> 7, ch = i & 127;
        int gch = 512 + ch;
        float acc = conv_b[gch];
#pragma unroll
        for (int k = 0; k < 4; k++)
            acc = fmaf(conv_w[gch * 4 + k], swin[r + k][ch], acc);
        float v = acc * __builtin_amdgcn_rcpf(1.f + __expf(-acc));
        BCb[(rowb + t0 + r) * 128 + ch] = v;
        sv[r][ch] = v;
    }
    __syncthreads();
    int wv = tid >> 6, lane = tid & 63;
    for (int r = wv; r < 25; r += 4) {
        float prod = sv[r][lane] * sv[r][64 + lane];
#pragma unroll
        for (int m = 1; m < 64; m <<= 1) prod += __shfl_xor(prod, m);
        if (lane == 0) BCF[rowb + t0 + r] = prod;
    }
}

// ---------------- selective scan v7b: old-state dot ----------------
__device__ __forceinline__ void sstep2(
    float raw, float dtv, float da, float bc,
    const float4& qb0, const float4& qb1, const float4& qb2, const float4& qb3,
    const float4& qc0, const float4& qc1, const float4& qc2, const float4& qc3,
    float cw0, float cw1, float cw2, float cw3, float cb, float ds,
    float* st, float& w0, float& w1, float& w2,
    int lane, float* __restrict__ yaddr)
{
    float cvv = cb + cw0 * w0 + cw1 * w1 + cw2 * w2 + cw3 * raw;
    float xhv = cvv * __builtin_amdgcn_rcpf(1.f + __expf(-cvv));
    w0 = w1; w1 = w2; w2 = raw;
    float xv = dtv * xhv;
    float p0 = st[0]  * qc0.x;
    float p1 = st[1]  * qc0.y;
    float p2 = st[2]  * qc0.z;
    float p3 = st[3]  * qc0.w;
    p0 = fmaf(st[4],  qc1.x, p0);
    p1 = fmaf(st[5],  qc1.y, p1);
    p2 = fmaf(st[6],  qc1.z, p2);
    p3 = fmaf(st[7],  qc1.w, p3);
    p0 = fmaf(st[8],  qc2.x, p0);
    p1 = fmaf(st[9],  qc2.y, p1);
    p2 = fmaf(st[10], qc2.z, p2);
    p3 = fmaf(st[11], qc2.w, p3);
    p0 = fmaf(st[12], qc3.x, p0);
    p1 = fmaf(st[13], qc3.y, p1);
    p2 = fmaf(st[14], qc3.z, p2);
    p3 = fmaf(st[15], qc3.w, p3);
    st[0]  = fmaf(da, st[0],  xv * qb0.x);
    st[1]  = fmaf(da, st[1],  xv * qb0.y);
    st[2]  = fmaf(da, st[2],  xv * qb0.z);
    st[3]  = fmaf(da, st[3],  xv * qb0.w);
    st[4]  = fmaf(da, st[4],  xv * qb1.x);
    st[5]  = fmaf(da, st[5],  xv * qb1.y);
    st[6]  = fmaf(da, st[6],  xv * qb1.z);
    st[7]  = fmaf(da, st[7],  xv * qb1.w);
    st[8]  = fmaf(da, st[8],  xv * qb2.x);
    st[9]  = fmaf(da, st[9],  xv * qb2.y);
    st[10] = fmaf(da, st[10], xv * qb2.z);
    st[11] = fmaf(da, st[11], xv * qb2.w);
    st[12] = fmaf(da, st[12], xv * qb3.x);
    st[13] = fmaf(da, st[13], xv * qb3.y);
    st[14] = fmaf(da, st[14], xv * qb3.z);
    st[15] = fmaf(da, st[15], xv * qb3.w);
    float part = (p0 + p1) + (p2 + p3);
    part += __shfl_xor(part, 16);
    part += __shfl_xor(part, 32);
    if (lane < HD) *yaddr = fmaf(da, part, fmaf(xv, bc, ds * xhv));
}

__global__ __launch_bounds__(256) void scan7b_kernel(
    const float* __restrict__ DTb, const float* __restrict__ DAb,
    float* __restrict__ XBC, const float* __restrict__ BCb,
    const float* __restrict__ Dsk,
    const float* __restrict__ conv_w, const float* __restrict__ conv_b,
    const float* __restrict__ BCF)
{
    __shared__ float sbc[2][TC][128];
    __shared__ unsigned short sx[2][TC][128];
    __shared__ float sdt[2][TC][8];
    __shared__ float sda[2][TC][8];
    __shared__ float sbcf[2][TC];
    int tid = threadIdx.x;
    int wv = tid >> 6, lane = tid & 63;
    int bid = blockIdx.x;
    int b = bid >> 2, hq = (bid & 3) * 8;
    long long rowb = (long long)b * SEQ;

    for (int i = tid; i < TC * 32; i += 256) {
        int r = i >> 5, c = i & 31;
        ((float4*)&sbc[0][r][0])[c] = ((const float4*)(BCb + (rowb + r) * 128))[c];
    }
    for (int i = tid; i < TC * 64; i += 256) {
        int r = i >> 6, c2 = i & 63;
        float2 v = *(const float2*)(XBC + (rowb + r) * XBCLD + hq * 16 + (c2 << 1));
        *(unsigned*)&sx[0][r][c2 << 1] = (unsigned)f2bf(v.x) | ((unsigned)f2bf(v.y) << 16);
    }
    for (int i = tid; i < TC * 8; i += 256) {
        int t = i >> 3, j = i & 7;
        sdt[0][t][j] = DTb[(rowb + t) * NH + hq + j];
        sda[0][t][j] = DAb[(rowb + t) * NH + hq + j];
    }
    if (tid < TC) sbcf[0][tid] = BCF[rowb + tid];
    __syncthreads();

    int p = lane & 15, g = lane >> 4;
    int hA = hq + wv, hB = hq + 4 + wv;
    int chA = hA * HD + p, chB = hB * HD + p;
    float cwA0 = conv_w[chA * 4 + 0], cwA1 = conv_w[chA * 4 + 1];
    float cwA2 = conv_w[chA * 4 + 2], cwA3 = conv_w[chA * 4 + 3];
    float cbA = conv_b[chA];
    float cwB0 = conv_w[chB * 4 + 0], cwB1 = conv_w[chB * 4 + 1];
    float cwB2 = conv_w[chB * 4 + 2], cwB3 = conv_w[chB * 4 + 3];
    float cbB = conv_b[chB];
    float dsA = Dsk[hA], dsB = Dsk[hB];
    int xcA = wv * 16 + p, xcB = (4 + wv) * 16 + p;
    float* ypA = XBC + rowb * XBCLD + hA * HD + p;
    float* ypB = XBC + rowb * XBCLD + hB * HD + p;
    float stA[16], stB[16];
#pragma unroll
    for (int r = 0; r < 16; r++) { stA[r] = 0.f; stB[r] = 0.f; }
    float wA0 = 0.f, wA1 = 0.f, wA2 = 0.f;
    float wB0 = 0.f, wB1 = 0.f, wB2 = 0.f;

    for (int c = 0; c < NCH; c++) {
        int cur = c & 1;
        if (c + 1 < NCH) {
            int nb = cur ^ 1;
            long long tb = rowb + (c + 1) * TC;
            for (int i = tid; i < TC * 32; i += 256) {
                int r = i >> 5, cc = i & 31;
                ((float4*)&sbc[nb][r][0])[cc] = ((const float4*)(BCb + (tb + r) * 128))[cc];
            }
            for (int i = tid; i < TC * 64; i += 256) {
                int r = i >> 6, c2 = i & 63;
                float2 v = *(const float2*)(XBC + (tb + r) * XBCLD + hq * 16 + (c2 << 1));
                *(unsigned*)&sx[nb][r][c2 << 1] = (unsigned)f2bf(v.x) | ((unsigned)f2bf(v.y) << 16);
            }
            for (int i = tid; i < TC * 8; i += 256) {
                int t = i >> 3, j = i & 7;
                sdt[nb][t][j] = DTb[(tb + t) * NH + hq + j];
                sda[nb][t][j] = DAb[(tb + t) * NH + hq + j];
            }
            if (tid < TC) sbcf[nb][tid] = BCF[tb + tid];
        }
        int tbase = c * TC;
        for (int t = 0; t < TC; t++) {
            int gt = tbase + t;
            const float4* qb = (const float4*)&sbc[cur][t][g * 16];
            const float4* qc = (const float4*)&sbc[cur][t][64 + g * 16];
            float4 qb0 = qb[0], qb1 = qb[1], qb2 = qb[2], qb3 = qb[3];
            float4 qc0 = qc[0], qc1 = qc[1], qc2 = qc[2], qc3 = qc[3];
            float rawA = bf2f(sx[cur][t][xcA]);
            float rawB = bf2f(sx[cur][t][xcB]);
            float bc = sbcf[cur][t];
            sstep2(rawA, sdt[cur][t][wv], sda[cur][t][wv], bc,
                   qb0, qb1, qb2, qb3, qc0, qc1, qc2, qc3,
                   cwA0, cwA1, cwA2, cwA3, cbA, dsA, stA, wA0, wA1, wA2,
                   lane, ypA + (long long)gt * XBCLD);
            sstep2(rawB, sdt[cur][t][4 + wv], sda[cur][t][4 + wv], bc,
                   qb0, qb1, qb2, qb3, qc0, qc1, qc2, qc3,
                   cwB0, cwB1, cwB2, cwB3, cbB, dsB, stB, wB0, wB1, wB2,
                   lane, ypB + (long long)gt * XBCLD);
        }
        __syncthreads();
    }
}

// ---------------- gate: G = rmsnorm(y * silu(z)) * w  (bf16 out, in-place) ----------------
__global__ __launch_bounds__(256) void gate_kernel(
    float* __restrict__ XBC, const unsigned short* __restrict__ Zbf,
    const float* __restrict__ rms_w)
{
    int row = blockIdx.x * 4 + (threadIdx.x >> 6);
    int lane = threadIdx.x & 63;
    float* yrow = XBC + (long long)row * XBCLD + lane * 8;
    const unsigned short* zrow = Zbf + (long long)row * 512 + lane * 8;
    float4 y0 = ((const float4*)yrow)[0];
    float4 y1 = ((const float4*)yrow)[1];
    uint4 zq = ((const uint4*)zrow)[0];
    float yv[8] = { y0.x, y0.y, y0.z, y0.w, y1.x, y1.y, y1.z, y1.w };
    float zv[8];
    zv[0] = bf2f((unsigned short)(zq.x & 0xFFFF)); zv[1] = bf2f((unsigned short)(zq.x >> 16));
    zv[2] = bf2f((unsigned short)(zq.y & 0xFFFF)); zv[3] = bf2f((unsigned short)(zq.y >> 16));
    zv[4] = bf2f((unsigned short)(zq.z & 0xFFFF)); zv[5] = bf2f((unsigned short)(zq.z >> 16));
    zv[6] = bf2f((unsigned short)(zq.w & 0xFFFF)); zv[7] = bf2f((unsigned short)(zq.w >> 16));
    float a[8]; float ss = 0.f;
#pragma unroll
    for (int i = 0; i < 8; i++) {
        float z = zv[i];
        a[i] = yv[i] * (z * __builtin_amdgcn_rcpf(1.f + __expf(-z)));
        ss = fmaf(a[i], a[i], ss);
    }
#pragma unroll
    for (int m = 1; m < 64; m <<= 1) ss += __shfl_xor(ss, m);
    float sc = rsqrtf(ss * (1.f / 512.f) + 1e-5f);
    const float* rw = rms_w + lane * 8;
    float4 r0 = ((const float4*)rw)[0];
    float4 r1 = ((const float4*)rw)[1];
    float rv[8] = { r0.x, r0.y, r0.z, r0.w, r1.x, r1.y, r1.z, r1.w };
    uint4 o;
    o.x = (unsigned)f2bf(a[0] * sc * rv[0]) | ((unsigned)f2bf(a[1] * sc * rv[1]) << 16);
    o.y = (unsigned)f2bf(a[2] * sc * rv[2]) | ((unsigned)f2bf(a[3] * sc * rv[3]) << 16);
    o.z = (unsigned)f2bf(a[4] * sc * rv[4]) | ((unsigned)f2bf(a[5] * sc * rv[5]) << 16);
    o.w = (unsigned)f2bf(a[6] * sc * rv[6]) | ((unsigned)f2bf(a[7] * sc * rv[7]) << 16);
    unsigned short* grow = (unsigned short*)(XBC + (long long)row * XBCLD);
    ((uint4*)grow)[lane] = o;
}

// ---------------- LayerNorm(bf16 a + bf16 b)*g+be -> f32 ----------------
__global__ void lnadd_bb_kernel(const unsigned short* __restrict__ A, const unsigned short* __restrict__ Bb,
                                const float* __restrict__ g, const float* __restrict__ be,
                                float* __restrict__ O)
{
    int row = blockIdx.x * 4 + (threadIdx.x >> 6);
    int lane = threadIdx.x & 63;
    long long base = (long long)row * DMODEL + lane * 4;
    float v[4]; float s1 = 0.f;
#pragma unroll
    for (int i = 0; i < 4; i++) { float a = bf2f(A[base + i]) + bf2f(Bb[base + i]); v[i] = a; s1 += a; }
#pragma unroll
    for (int m = 1; m < 64; m <<= 1) s1 += __shfl_xor(s1, m);
    float mean = s1 * (1.f / 256.f);
    float s2 = 0.f;
#pragma unroll
    for (int i = 0; i < 4; i++) { float d = v[i] - mean; s2 = fmaf(d, d, s2); }
#pragma unroll
    for (int m = 1; m < 64; m <<= 1) s2 += __shfl_xor(s2, m);
    float r = rsqrtf(s2 * (1.f / 256.f) + 1e-12f);
#pragma unroll
    for (int i = 0; i < 4; i++)
        O[base + i] = (v[i] - mean) * r * g[lane * 4 + i] + be[lane * 4 + i];
}

// ---------------- fused: H = alpha*LN(MO+x) + beta*LN(XI+x) -> bf16 HB ----------------
__global__ void combine2_kernel(const unsigned short* __restrict__ XI, const float* __restrict__ X,
                                const float* __restrict__ MO, unsigned short* __restrict__ HB,
                                const float* __restrict__ lg, const float* __restrict__ lb,
                                const float* __restrict__ fg, const float* __restrict__ fb,
                                const float* __restrict__ al, const float* __restrict__ bt)
{
    int row = blockIdx.x * 4 + (threadIdx.x >> 6);
    int lane = threadIdx.x & 63;
    long long base = (long long)row * DMODEL + lane * 4;
    int bb = row / SEQ, ll = row - bb * SEQ;
    long long xib = (long long)bb * 65536 + ll * 256 + lane * 4;
    float u[4], v[4]; float su = 0.f, sv = 0.f;
#pragma unroll
    for (int i = 0; i < 4; i++) {
        float xv = X[base + i];
        float a = MO[base + i] + xv;
        float b = bf2f(XI[xib + i]) + xv;
        u[i] = a; v[i] = b; su += a; sv += b;
    }
#pragma unroll
    for (int m = 1; m < 64; m <<= 1) { su += __shfl_xor(su, m); sv += __shfl_xor(sv, m); }
    float mu = su * (1.f / 256.f), mv = sv * (1.f / 256.f);
    float qu = 0.f, qv = 0.f;
#pragma unroll
    for (int i = 0; i < 4; i++) {
        float du = u[i] - mu; qu = fmaf(du, du, qu);
        float dv = v[i] - mv; qv = fmaf(dv, dv, qv);
    }
#pragma unroll
    for (int m = 1; m < 64; m <<= 1) { qu += __shfl_xor(qu, m); qv += __shfl_xor(qv, m); }
    float ru = rsqrtf(qu * (1.f / 256.f) + 1e-12f);
    float rv = rsqrtf(qv * (1.f / 256.f) + 1e-12f);
#pragma unroll
    for (int i = 0; i < 4; i++) {
        int d = lane * 4 + i;
        float h1 = (u[i] - mu) * ru * lg[d] + lb[d];
        float h2 = (v[i] - mv) * rv * fg[d] + fb[d];
        float h = al[d] * h1 + bt[d] * h2;
        HB[base + i] = f2bf(h);
    }
}

// ---------------- pointwise spectral filter on XFT[b][d][j] bf16 (ld 256) ----------------
__global__ void filt_kernel(unsigned short* __restrict__ XF, const float* __restrict__ W)
{
    long long idx = (long long)blockIdx.x * 256 + threadIdx.x;
    if (idx >= (long long)BATCHN * DMODEL * NF) return;
    int f = (int)(idx % NF);
    int d = (int)((idx / NF) % DMODEL);
    int b = (int)(idx / ((long long)NF * DMODEL));
    long long base = ((long long)b * DMODEL + d) * 256;
    float re = bf2f(XF[base + f]);
    float im = bf2f(XF[base + 101 + f]);
    float wr = W[((long long)f * DMODEL + d) * 2];
    float wi = W[((long long)f * DMODEL + d) * 2 + 1];
    XF[base + f]       = f2bf(re * wr - im * wi);
    XF[base + 101 + f] = f2bf(re * wi + im * wr);
}

extern "C" void kernel_launch(void* const* d_in, const int* in_sizes, int n_in,
                              void* d_out, int out_size, void* d_ws, size_t ws_size,
                              hipStream_t stream)
{
    const float* x          = (const float*)d_in[0];
    const float* in_proj_w  = (const float*)d_in[1];
    const float* conv_w     = (const float*)d_in[2];
    const float* conv_b     = (const float*)d_in[3];
    const float* dt_bias    = (const float*)d_in[4];
    const float* A_log      = (const float*)d_in[5];
    const float* D_skip     = (const float*)d_in[6];
    const float* rms_w      = (const float*)d_in[7];
    const float* out_proj_w = (const float*)d_in[8];
    const float* ln_g       = (const float*)d_in[9];
    const float* ln_b       = (const float*)d_in[10];
    const float* filt_w     = (const float*)d_in[11];
    const float* filt_ln_g  = (const float*)d_in[12];
    const float* filt_ln_b  = (const float*)d_in[13];
    const float* alpha      = (const float*)d_in[14];
    const float* beta       = (const float*)d_in[15];
    const float* ffn_w1     = (const float*)d_in[16];
    const float* ffn_b1     = (const float*)d_in[17];
    const float* ffn_w2     = (const float*)d_in[18];
    const float* ffn_b2     = (const float*)d_in[19];
    const float* ffn_ln_g   = (const float*)d_in[20];
    const float* ffn_ln_b   = (const float*)d_in[21];
    float* out = (float*)d_out;
    float* ws = (float*)d_ws;

    // weights arena [81920 .. XBASE)
    unsigned short* WP    = (unsigned short*)(ws + 81920);
    unsigned short* wTall = WP;                  // 1184*256
    unsigned short* opwT  = wTall + 1184 * 256;  // 256*512
    unsigned short* w1T   = opwT + 256 * 512;    // 1024*256
    unsigned short* w2T   = w1T + 1024 * 256;    // 256*1024
    unsigned short* EFbf  = w2T + 256 * 1024;    // 256*200
    unsigned short* EIbf  = EFbf + 256 * SEQ;    // 256*256
    float* XBC = ws + XBASE;                     // BL*672 f32 arena
    float* BCb = XBC + (long long)BL * XBCLD;    // BL*128
    float* DTb = BCb + (long long)BL * 128;      // BL*32
    float* DAb = DTb + (long long)BL * NH;       // BL*32
    float* MO  = DAb + (long long)BL * NH;       // BL*256 (h1 pre-LN)
    float* BCF = MO + (long long)BL * DMODEL;    // BL  (b·c per row)
    unsigned short* Zbf = (unsigned short*)MO;   // BL*512 bf16, lifetime [proj..gate]
    // BCb region reuse:
    unsigned short* xbf  = (unsigned short*)BCb; // bf16 x, lifetime [setup..proj]
    unsigned short* xTbf = (unsigned short*)BCb; // lifetime [xT..FFT fwd]
    unsigned short* MObf = (unsigned short*)BCb; // bf16 H, lifetime [combine2..lnadd_bb]
    // XBC arena reuse:
    unsigned short* Gbf = (unsigned short*)XBC;              // bf16 G in place, ld 1344
    unsigned short* XFT = (unsigned short*)XBC;              // 256*256*256 bf16
    unsigned short* XI  = (unsigned short*)(XBC + XIOFF);    // 256*65536 bf16
    unsigned short* HID = (unsigned short*)XBC;              // BL*1024 bf16 (post-combine2)
    unsigned short* FFO = (unsigned short*)(XBC + 26500000); // BL*256 bf16

    // 1. DFT matrices + merged setup (packs + x->bf16)
    init_dft_kernel<<<dim3((256 * SEQ + 256 * 256 + 255) / 256), dim3(256), 0, stream>>>(EFbf, EIbf);
    setup_kernel<<<dim3((S0 + S1 + S2 + S3 + S4) / 256), dim3(256), 0, stream>>>(
        in_proj_w, out_proj_w, ffn_w1, ffn_w2, x, wTall, opwT, w1T, w2T, xbf);

    // 2. merged projection: xbf[BL,256] @ wTall^T -> Zbf (cols<512) + XBC (cols>=512)
    mgemm_proj<<<dim3(10, BL / 128), dim3(256), 0, stream>>>(xbf, wTall, XBC, Zbf);

    // 3. conv+silu B/C; dt -> DT/DA; bc -> BCF (clobbers xbf)
    convbc2_kernel<<<dim3(BATCHN * 8), dim3(256), 0, stream>>>(XBC, conv_w, conv_b, dt_bias,
                                                               A_log, BCb, DTb, DAb, BCF);

    // 4. scan v7b, y in place f32
    scan7b_kernel<<<dim3(BATCHN * 4), dim3(256), 0, stream>>>(DTb, DAb, XBC, BCb, D_skip,
                                                              conv_w, conv_b, BCF);

    // 4.5 x transpose -> xTbf (BCb dead after scan)
    xT_kernel<<<dim3(7, 8, BATCHN), dim3(256), 0, stream>>>(x, xTbf);

    // 5. gate -> Gbf bf16 in place
    gate_kernel<<<dim3(BL / 4), dim3(256), 0, stream>>>(XBC, Zbf, rms_w);

    // 6. out_proj: Gbf[BL,512](ld 1344) @ opwT^T -> MO f32 (Zbf dead)
    mgemm_kernel<0,0><<<dim3(2, BL / 128, 1), dim3(256), 0, stream>>>(
        Gbf, opwT, MO, nullptr, BL, 256, 512, 1344, 512, 256, 0, 0, 0);

    // 7. FFT fwd: XFT[b][256][256] = xTbf[b][256,200] @ EFbf[256,200]^T, bf16 (ld 256)
    mgemm_kernel<0,1><<<dim3(2, 2, BATCHN), dim3(256), 0, stream>>>(
        xTbf, EFbf, XFT, nullptr, 256, 256, SEQ, SEQ, SEQ, 256,
        (long long)DMODEL * SEQ, 0, 65536);

    // 8. spectral filter in place
    filt_kernel<<<dim3((BATCHN * DMODEL * NF + 255) / 256), dim3(256), 0, stream>>>(XFT, filt_w);

    // 9. FFT inv: XI[b][256][256] = EIbf[256,256] @ XFT[b]^T, bf16 out (batch stride 65536)
    mgemm_kernel<0,1><<<dim3(2, 2, BATCHN), dim3(256), 0, stream>>>(
        EIbf, XFT, XI, nullptr, 256, 256, 256, 256, 256, 256,
        0, 65536, 65536);

    // 10. fused combine -> bf16 H only (MObf; xTbf dead)
    combine2_kernel<<<dim3(BL / 4), dim3(256), 0, stream>>>(XI, x, MO, MObf,
                                                            ln_g, ln_b, filt_ln_g, filt_ln_b,
                                                            alpha, beta);

    // 11. FFN1: MObf[BL,256] @ w1T^T + b1, GELU -> HID bf16 (XI dead)
    mgemm_kernel<1,1><<<dim3(8, BL / 128, 1), dim3(256), 0, stream>>>(
        MObf, w1T, HID, ffn_b1, BL, 1024, 256, 256, 256, 1024, 0, 0, 0);

    // 12. FFN2: HID[BL,1024] @ w2T^T + b2 -> FFO bf16
    mgemm_kernel<0,1><<<dim3(2, BL / 128, 1), dim3(256), 0, stream>>>(
        HID, w2T, FFO, ffn_b2, BL, 256, 1024, 1024, 1024, 256, 0, 0, 0);

    // 13. out = LN(FFO + H)
    lnadd_bb_kernel<<<dim3(BL / 4), dim3(256), 0, stream>>>(FFO, MObf, ffn_ln_g, ffn_ln_b, out);
}

// Round 16
// 778.661 us; speedup vs baseline: 1.0332x; 1.0106x over previous
//
#include <hip/hip_runtime.h>
#include <math.h>

#define BATCHN 256
#define SEQ 200
#define DMODEL 256
#define DINNER 512
#define NH 32
#define HD 16
#define DSTATE 64
#define DINPROJ 1184
#define XBCLD 672
#define BL (BATCHN*SEQ)   // 51200
#define NF 101
#define XBASE 655360
#define TC 20
#define NCH 10
#define XIOFF 8500000     // f32 offset of XI within XBC arena

typedef __attribute__((ext_vector_type(8))) short bf16x8;
typedef __attribute__((ext_vector_type(4))) float f32x4;

__device__ inline unsigned short f2bf(float f) {
    union { float f; unsigned u; } v; v.f = f;
    unsigned r = v.u + 0x7FFFu + ((v.u >> 16) & 1u);
    return (unsigned short)(r >> 16);
}
__device__ inline float bf2f(unsigned short h) {
    union { unsigned u; float f; } v; v.u = ((unsigned)h) << 16;
    return v.f;
}

#define GLOAD16(src, dst) __builtin_amdgcn_global_load_lds( \
    (const __attribute__((address_space(1))) void*)(src),   \
    (__attribute__((address_space(3))) void*)(dst), 16, 0, 0)

// ---------------- DFT matrices (bf16, padded to 256) ----------------
__global__ void init_dft_kernel(unsigned short* __restrict__ EF, unsigned short* __restrict__ EI)
{
    const float ang = 6.28318530717958647692f / 200.0f;
    int idx = blockIdx.x * 256 + threadIdx.x;
    if (idx < 256 * SEQ) {
        int f = idx / SEQ, t = idx - f * SEQ;
        float v;
        if (f <= 100) { int ph = (f * t) % 200; v = cosf(ang * (float)ph); }
        else if (f <= 201) { int ff = f - 101; int ph = (ff * t) % 200; v = -sinf(ang * (float)ph); }
        else v = 0.f;
        EF[idx] = f2bf(v);
    } else if (idx < 256 * SEQ + 256 * 256) {
        int j2 = idx - 256 * SEQ;
        int t = j2 >> 8, j = j2 & 255;
        float v;
        if (t >= 200) v = 0.f;
        else if (j == 0) v = 1.0f / 200.0f;
        else if (j == 100) v = ((t & 1) ? -1.0f : 1.0f) / 200.0f;
        else if (j < 100) { int ph = (j * t) % 200; v = 2.0f * cosf(ang * (float)ph) / 200.0f; }
        else if (j >= 202 || j == 101 || j == 201) v = 0.0f;
        else { int f = j - 101; int ph = (f * t) % 200; v = -2.0f * sinf(ang * (float)ph) / 200.0f; }
        EI[j2] = f2bf(v);
    }
}

// ---------------- merged setup: weight packs + x->bf16 ----------------
#define S0 303104   // wTall 1184*256
#define S1 131072   // opwT 256*512
#define S2 262144   // w1T 1024*256
#define S3 262144   // w2T 256*1024
#define S4 1638400  // f2bf groups of 8
__global__ void setup_kernel(const float* __restrict__ ipw, const float* __restrict__ opw,
                             const float* __restrict__ w1, const float* __restrict__ w2,
                             const float* __restrict__ X,
                             unsigned short* __restrict__ wTall, unsigned short* __restrict__ opwT,
                             unsigned short* __restrict__ w1T, unsigned short* __restrict__ w2T,
                             unsigned short* __restrict__ xbf)
{
    long long idx = (long long)blockIdx.x * 256 + threadIdx.x;
    if (idx < S0) { int n = (int)(idx / 256), k = (int)(idx % 256);
        wTall[idx] = f2bf(ipw[(long long)k * DINPROJ + n]); return; }
    idx -= S0;
    if (idx < S1) { int n = (int)(idx / 512), k = (int)(idx % 512);
        opwT[idx] = f2bf(opw[(long long)k * 256 + n]); return; }
    idx -= S1;
    if (idx < S2) { int n = (int)(idx / 256), k = (int)(idx % 256);
        w1T[idx] = f2bf(w1[(long long)k * 1024 + n]); return; }
    idx -= S2;
    if (idx < S3) { int n = (int)(idx / 1024), k = (int)(idx % 1024);
        w2T[idx] = f2bf(w2[(long long)k * 256 + n]); return; }
    idx -= S3;
    if (idx < S4) {
        long long i = idx * 8;
        float4 a = ((const float4*)(X + i))[0];
        float4 b = ((const float4*)(X + i))[1];
        uint4 o;
        o.x = (unsigned)f2bf(a.x) | ((unsigned)f2bf(a.y) << 16);
        o.y = (unsigned)f2bf(a.z) | ((unsigned)f2bf(a.w) << 16);
        o.z = (unsigned)f2bf(b.x) | ((unsigned)f2bf(b.y) << 16);
        o.w = (unsigned)f2bf(b.z) | ((unsigned)f2bf(b.w) << 16);
        *(uint4*)(xbf + i) = o;
    }
}

// ---------------- x transpose: xT[b][d][t] = bf16(x[b][t][d]) ----------------
__global__ void xT_kernel(const float* __restrict__ X, unsigned short* __restrict__ XT)
{
    __shared__ float tile[32][33];
    int b = blockIdx.z, t0 = blockIdx.x * 32, d0 = blockIdx.y * 32;
    int tx = threadIdx.x & 31, ty = threadIdx.x >> 5;
    const float* xb = X + (long long)b * SEQ * DMODEL;
#pragma unroll
    for (int i = 0; i < 4; i++) {
        int t = t0 + ty + i * 8;
        tile[ty + i * 8][tx] = (t < SEQ) ? xb[(long long)t * DMODEL + d0 + tx] : 0.f;
    }
    __syncthreads();
    unsigned short* xtb = XT + (long long)b * DMODEL * SEQ;
#pragma unroll
    for (int i = 0; i < 4; i++) {
        int d = d0 + ty + i * 8;
        int t = t0 + tx;
        if (t < SEQ) xtb[(long long)d * SEQ + t] = f2bf(tile[tx][ty + i * 8]);
    }
}

// ---------------- bf16 MFMA GEMM: BK=32, global_load_lds, linear LDS ----------------
template<int ACT, int CBF>
__global__ __launch_bounds__(256) void mgemm_kernel(
    const unsigned short* __restrict__ Ab, const unsigned short* __restrict__ BTp,
    void* __restrict__ Cp, const float* __restrict__ bias,
    int M, int N, int K, int lda, int ldbt, int ldc,
    long long sA, long long sBT, long long sC)
{
    __shared__ unsigned short As[128 * 32];
    __shared__ unsigned short Bs[128 * 32];
    const unsigned short* Aa = Ab + (long long)blockIdx.z * sA;
    const unsigned short* Bt = BTp + (long long)blockIdx.z * sBT;
    float* Cf = (float*)Cp + (CBF ? 0 : (long long)blockIdx.z * sC);
    unsigned short* Cb = (unsigned short*)Cp + (CBF ? (long long)blockIdx.z * sC : 0);

    int m0 = blockIdx.y * 128, n0 = blockIdx.x * 128;
    int tid = threadIdx.x;
    int srow = tid >> 1, skb = (tid & 1) * 16;
    int w = tid >> 6, l = tid & 63;
    int wr = w >> 1, wc = w & 1;
    int fr = l & 15, fk = l >> 4;
    int glr = (w << 4) + (l >> 2);
    int glc = (l & 3) << 3;
    bool fullM = (m0 + 128 <= M);
    bool fullN = (n0 + 128 <= N);

    f32x4 acc[4][4] = {};

    for (int k0 = 0; k0 < K; k0 += 32) {
        bool kedge = (k0 + 32 > K);
        if (fullM && !kedge) {
            GLOAD16(Aa + (long long)(m0 + glr) * lda + k0 + glc,      &As[w << 9]);
            GLOAD16(Aa + (long long)(m0 + 64 + glr) * lda + k0 + glc, &As[2048 + (w << 9)]);
        } else {
            int gm = m0 + srow;
            unsigned short* dst = &As[srow * 32 + skb];
#pragma unroll
            for (int i = 0; i < 16; i++) {
                int gk = k0 + skb + i;
                dst[i] = (gm < M && gk < K) ? Aa[(long long)gm * lda + gk] : (unsigned short)0;
            }
        }
        if (fullN && !kedge) {
            GLOAD16(Bt + (long long)(n0 + glr) * ldbt + k0 + glc,      &Bs[w << 9]);
            GLOAD16(Bt + (long long)(n0 + 64 + glr) * ldbt + k0 + glc, &Bs[2048 + (w << 9)]);
        } else {
            int gn = n0 + srow;
            unsigned short* dst = &Bs[srow * 32 + skb];
#pragma unroll
            for (int i = 0; i < 16; i++) {
                int gk = k0 + skb + i;
                dst[i] = (gn < N && gk < K) ? Bt[(long long)gn * ldbt + gk] : (unsigned short)0;
            }
        }
        __syncthreads();
        bf16x8 a[4], b[4];
#pragma unroll
        for (int i = 0; i < 4; i++) {
            a[i] = *(const bf16x8*)&As[(wr * 64 + i * 16 + fr) * 32 + fk * 8];
            b[i] = *(const bf16x8*)&Bs[(wc * 64 + i * 16 + fr) * 32 + fk * 8];
        }
#pragma unroll
        for (int i = 0; i < 4; i++)
#pragma unroll
            for (int j = 0; j < 4; j++)
                acc[i][j] = __builtin_amdgcn_mfma_f32_16x16x32_bf16(a[i], b[j], acc[i][j], 0, 0, 0);
        __syncthreads();
    }

#pragma unroll
    for (int i = 0; i < 4; i++) {
        int gr0 = m0 + wr * 64 + i * 16 + fk * 4;
#pragma unroll
        for (int j = 0; j < 4; j++) {
            int gc = n0 + wc * 64 + j * 16 + fr;
            if (gc >= N) continue;
            float bv = bias ? bias[gc] : 0.f;
#pragma unroll
            for (int r = 0; r < 4; r++) {
                int gr = gr0 + r;
                if (gr >= M) continue;
                float v = acc[i][j][r] + bv;
                if (ACT == 1) v = 0.5f * v * (1.f + erff(v * 0.70710678118654752f));
                long long ci = (long long)gr * ldc + gc;
                if (CBF) Cb[ci] = f2bf(v);
                else Cf[ci] = v;
            }
        }
    }
}

// ---------------- merged projection GEMM: N=1184; cols<512 -> Zbf, >=512 -> XBC ----------------
__global__ __launch_bounds__(256) void mgemm_proj(
    const unsigned short* __restrict__ Aa, const unsigned short* __restrict__ Bt,
    float* __restrict__ XBCout, unsigned short* __restrict__ Zout)
{
    __shared__ unsigned short As[128 * 32];
    __shared__ unsigned short Bs[128 * 32];
    const int N = DINPROJ;
    int m0 = blockIdx.y * 128, n0 = blockIdx.x * 128;
    int tid = threadIdx.x;
    int srow = tid >> 1, skb = (tid & 1) * 16;
    int w = tid >> 6, l = tid & 63;
    int wr = w >> 1, wc = w & 1;
    int fr = l & 15, fk = l >> 4;
    int glr = (w << 4) + (l >> 2);
    int glc = (l & 3) << 3;
    bool fullN = (n0 + 128 <= N);

    f32x4 acc[4][4] = {};

    for (int k0 = 0; k0 < 256; k0 += 32) {
        GLOAD16(Aa + (long long)(m0 + glr) * 256 + k0 + glc,      &As[w << 9]);
        GLOAD16(Aa + (long long)(m0 + 64 + glr) * 256 + k0 + glc, &As[2048 + (w << 9)]);
        if (fullN) {
            GLOAD16(Bt + (long long)(n0 + glr) * 256 + k0 + glc,      &Bs[w << 9]);
            GLOAD16(Bt + (long long)(n0 + 64 + glr) * 256 + k0 + glc, &Bs[2048 + (w << 9)]);
        } else {
            int gn = n0 + srow;
            unsigned short* dst = &Bs[srow * 32 + skb];
#pragma unroll
            for (int i = 0; i < 16; i++)
                dst[i] = (gn < N) ? Bt[(long long)gn * 256 + k0 + skb + i] : (unsigned short)0;
        }
        __syncthreads();
        bf16x8 a[4], b[4];
#pragma unroll
        for (int i = 0; i < 4; i++) {
            a[i] = *(const bf16x8*)&As[(wr * 64 + i * 16 + fr) * 32 + fk * 8];
            b[i] = *(const bf16x8*)&Bs[(wc * 64 + i * 16 + fr) * 32 + fk * 8];
        }
#pragma unroll
        for (int i = 0; i < 4; i++)
#pragma unroll
            for (int j = 0; j < 4; j++)
                acc[i][j] = __builtin_amdgcn_mfma_f32_16x16x32_bf16(a[i], b[j], acc[i][j], 0, 0, 0);
        __syncthreads();
    }

#pragma unroll
    for (int i = 0; i < 4; i++) {
        int gr0 = m0 + wr * 64 + i * 16 + fk * 4;
#pragma unroll
        for (int j = 0; j < 4; j++) {
            int gc = n0 + wc * 64 + j * 16 + fr;
            if (gc >= N) continue;
#pragma unroll
            for (int r = 0; r < 4; r++) {
                int gr = gr0 + r;
                float v = acc[i][j][r];
                if (gc < 512) Zout[(long long)gr * 512 + gc] = f2bf(v);
                else XBCout[(long long)gr * XBCLD + (gc - 512)] = v;
            }
        }
    }
}

// ---------------- convbc v2: 25-row chunks, LDS window ----------------
__global__ __launch_bounds__(256) void convbc2_kernel(
    const float* __restrict__ XBC, const float* __restrict__ conv_w,
    const float* __restrict__ conv_b, const float* __restrict__ dt_bias,
    const float* __restrict__ A_log,
    float* __restrict__ BCb, float* __restrict__ DTb, float* __restrict__ DAb,
    float* __restrict__ BCF)
{
    __shared__ float swin[28][128];
    __shared__ float sv[25][128];
    int tid = threadIdx.x;
    int bid = blockIdx.x;
    int b = bid >> 3, c = bid & 7;
    int t0 = c * 25;
    long long rowb = (long long)b * SEQ;
    for (int i = tid; i < 28 * 32; i += 256) {
        int r = i >> 5, q = i & 31;
        int t = t0 - 3 + r;
        float4 v = (t >= 0) ? ((const float4*)(XBC + (rowb + t) * XBCLD + 512))[q]
                            : (float4){0.f, 0.f, 0.f, 0.f};
        ((float4*)&swin[r][0])[q] = v;
    }
    for (int i = tid; i < 25 * 32; i += 256) {
        int r = i >> 5, h = i & 31;
        long long row = rowb + t0 + r;
        float draw = XBC[row * XBCLD + 640 + h] + dt_bias[h];
        float dtv = (draw > 20.f) ? draw : log1pf(__expf(draw));
        DTb[row * NH + h] = dtv;
        DAb[row * NH + h] = __expf(-__expf(A_log[h]) * dtv);
    }
    __syncthreads();
    for (int i = tid; i < 25 * 128; i += 256) {
        int r = i >> 7, ch = i & 127;
        int gch = 512 + ch;
        float acc = conv_b[gch];
#pragma unroll
        for (int k = 0; k < 4; k++)
            acc = fmaf(conv_w[gch * 4 + k], swin[r + k][ch], acc);
        float v = acc * __builtin_amdgcn_rcpf(1.f + __expf(-acc));
        BCb[(rowb + t0 + r) * 128 + ch] = v;
        sv[r][ch] = v;
    }
    __syncthreads();
    int wv = tid >> 6, lane = tid & 63;
    for (int r = wv; r < 25; r += 4) {
        float prod = sv[r][lane] * sv[r][64 + lane];
#pragma unroll
        for (int m = 1; m < 64; m <<= 1) prod += __shfl_xor(prod, m);
        if (lane == 0) BCF[rowb + t0 + r] = prod;
    }
}

// ---------------- selective scan v7c: old-state dot, bf16 y in place ----------------
__device__ __forceinline__ void sstep2(
    float raw, float dtv, float da, float bc,
    const float4& qb0, const float4& qb1, const float4& qb2, const float4& qb3,
    const float4& qc0, const float4& qc1, const float4& qc2, const float4& qc3,
    float cw0, float cw1, float cw2, float cw3, float cb, float ds,
    float* st, float& w0, float& w1, float& w2,
    int lane, unsigned short* __restrict__ yaddr)
{
    float cvv = cb + cw0 * w0 + cw1 * w1 + cw2 * w2 + cw3 * raw;
    float xhv = cvv * __builtin_amdgcn_rcpf(1.f + __expf(-cvv));
    w0 = w1; w1 = w2; w2 = raw;
    float xv = dtv * xhv;
    float p0 = st[0]  * qc0.x;
    float p1 = st[1]  * qc0.y;
    float p2 = st[2]  * qc0.z;
    float p3 = st[3]  * qc0.w;
    p0 = fmaf(st[4],  qc1.x, p0);
    p1 = fmaf(st[5],  qc1.y, p1);
    p2 = fmaf(st[6],  qc1.z, p2);
    p3 = fmaf(st[7],  qc1.w, p3);
    p0 = fmaf(st[8],  qc2.x, p0);
    p1 = fmaf(st[9],  qc2.y, p1);
    p2 = fmaf(st[10], qc2.z, p2);
    p3 = fmaf(st[11], qc2.w, p3);
    p0 = fmaf(st[12], qc3.x, p0);
    p1 = fmaf(st[13], qc3.y, p1);
    p2 = fmaf(st[14], qc3.z, p2);
    p3 = fmaf(st[15], qc3.w, p3);
    st[0]  = fmaf(da, st[0],  xv * qb0.x);
    st[1]  = fmaf(da, st[1],  xv * qb0.y);
    st[2]  = fmaf(da, st[2],  xv * qb0.z);
    st[3]  = fmaf(da, st[3],  xv * qb0.w);
    st[4]  = fmaf(da, st[4],  xv * qb1.x);
    st[5]  = fmaf(da, st[5],  xv * qb1.y);
    st[6]  = fmaf(da, st[6],  xv * qb1.z);
    st[7]  = fmaf(da, st[7],  xv * qb1.w);
    st[8]  = fmaf(da, st[8],  xv * qb2.x);
    st[9]  = fmaf(da, st[9],  xv * qb2.y);
    st[10] = fmaf(da, st[10], xv * qb2.z);
    st[11] = fmaf(da, st[11], xv * qb2.w);
    st[12] = fmaf(da, st[12], xv * qb3.x);
    st[13] = fmaf(da, st[13], xv * qb3.y);
    st[14] = fmaf(da, st[14], xv * qb3.z);
    st[15] = fmaf(da, st[15], xv * qb3.w);
    float part = (p0 + p1) + (p2 + p3);
    part += __shfl_xor(part, 16);
    part += __shfl_xor(part, 32);
    if (lane < HD) *yaddr = f2bf(fmaf(da, part, fmaf(xv, bc, ds * xhv)));
}

__global__ __launch_bounds__(256) void scan7b_kernel(
    const float* __restrict__ DTb, const float* __restrict__ DAb,
    float* __restrict__ XBC, const float* __restrict__ BCb,
    const float* __restrict__ Dsk,
    const float* __restrict__ conv_w, const float* __restrict__ conv_b,
    const float* __restrict__ BCF)
{
    __shared__ float sbc[2][TC][128];
    __shared__ unsigned short sx[2][TC][128];
    __shared__ float sdt[2][TC][8];
    __shared__ float sda[2][TC][8];
    __shared__ float sbcf[2][TC];
    int tid = threadIdx.x;
    int wv = tid >> 6, lane = tid & 63;
    int bid = blockIdx.x;
    int b = bid >> 2, hq = (bid & 3) * 8;
    long long rowb = (long long)b * SEQ;

    for (int i = tid; i < TC * 32; i += 256) {
        int r = i >> 5, c = i & 31;
        ((float4*)&sbc[0][r][0])[c] = ((const float4*)(BCb + (rowb + r) * 128))[c];
    }
    for (int i = tid; i < TC * 64; i += 256) {
        int r = i >> 6, c2 = i & 63;
        float2 v = *(const float2*)(XBC + (rowb + r) * XBCLD + hq * 16 + (c2 << 1));
        *(unsigned*)&sx[0][r][c2 << 1] = (unsigned)f2bf(v.x) | ((unsigned)f2bf(v.y) << 16);
    }
    for (int i = tid; i < TC * 8; i += 256) {
        int t = i >> 3, j = i & 7;
        sdt[0][t][j] = DTb[(rowb + t) * NH + hq + j];
        sda[0][t][j] = DAb[(rowb + t) * NH + hq + j];
    }
    if (tid < TC) sbcf[0][tid] = BCF[rowb + tid];
    __syncthreads();

    int p = lane & 15, g = lane >> 4;
    int hA = hq + wv, hB = hq + 4 + wv;
    int chA = hA * HD + p, chB = hB * HD + p;
    float cwA0 = conv_w[chA * 4 + 0], cwA1 = conv_w[chA * 4 + 1];
    float cwA2 = conv_w[chA * 4 + 2], cwA3 = conv_w[chA * 4 + 3];
    float cbA = conv_b[chA];
    float cwB0 = conv_w[chB * 4 + 0], cwB1 = conv_w[chB * 4 + 1];
    float cwB2 = conv_w[chB * 4 + 2], cwB3 = conv_w[chB * 4 + 3];
    float cbB = conv_b[chB];
    float dsA = Dsk[hA], dsB = Dsk[hB];
    int xcA = wv * 16 + p, xcB = (4 + wv) * 16 + p;
    // bf16 y packed in the block's own column range:
    // head h -> ushort offset hq*32 + (h-hq)*16 + p, row stride 1344 ushorts
    unsigned short* ybase = (unsigned short*)(XBC + rowb * XBCLD);
    unsigned short* ypA = ybase + hq * 32 + wv * 16 + p;
    unsigned short* ypB = ybase + hq * 32 + (4 + wv) * 16 + p;
    float stA[16], stB[16];
#pragma unroll
    for (int r = 0; r < 16; r++) { stA[r] = 0.f; stB[r] = 0.f; }
    float wA0 = 0.f, wA1 = 0.f, wA2 = 0.f;
    float wB0 = 0.f, wB1 = 0.f, wB2 = 0.f;

    for (int c = 0; c < NCH; c++) {
        int cur = c & 1;
        if (c + 1 < NCH) {
            int nb = cur ^ 1;
            long long tb = rowb + (c + 1) * TC;
            for (int i = tid; i < TC * 32; i += 256) {
                int r = i >> 5, cc = i & 31;
                ((float4*)&sbc[nb][r][0])[cc] = ((const float4*)(BCb + (tb + r) * 128))[cc];
            }
            for (int i = tid; i < TC * 64; i += 256) {
                int r = i >> 6, c2 = i & 63;
                float2 v = *(const float2*)(XBC + (tb + r) * XBCLD + hq * 16 + (c2 << 1));
                *(unsigned*)&sx[nb][r][c2 << 1] = (unsigned)f2bf(v.x) | ((unsigned)f2bf(v.y) << 16);
            }
            for (int i = tid; i < TC * 8; i += 256) {
                int t = i >> 3, j = i & 7;
                sdt[nb][t][j] = DTb[(tb + t) * NH + hq + j];
                sda[nb][t][j] = DAb[(tb + t) * NH + hq + j];
            }
            if (tid < TC) sbcf[nb][tid] = BCF[tb + tid];
        }
        int tbase = c * TC;
        for (int t = 0; t < TC; t++) {
            int gt = tbase + t;
            const float4* qb = (const float4*)&sbc[cur][t][g * 16];
            const float4* qc = (const float4*)&sbc[cur][t][64 + g * 16];
            float4 qb0 = qb[0], qb1 = qb[1], qb2 = qb[2], qb3 = qb[3];
            float4 qc0 = qc[0], qc1 = qc[1], qc2 = qc[2], qc3 = qc[3];
            float rawA = bf2f(sx[cur][t][xcA]);
            float rawB = bf2f(sx[cur][t][xcB]);
            float bc = sbcf[cur][t];
            sstep2(rawA, sdt[cur][t][wv], sda[cur][t][wv], bc,
                   qb0, qb1, qb2, qb3, qc0, qc1, qc2, qc3,
                   cwA0, cwA1, cwA2, cwA3, cbA, dsA, stA, wA0, wA1, wA2,
                   lane, ypA + (long long)gt * 1344);
            sstep2(rawB, sdt[cur][t][4 + wv], sda[cur][t][4 + wv], bc,
                   qb0, qb1, qb2, qb3, qc0, qc1, qc2, qc3,
                   cwB0, cwB1, cwB2, cwB3, cbB, dsB, stB, wB0, wB1, wB2,
                   lane, ypB + (long long)gt * 1344);
        }
        __syncthreads();
    }
}

// ---------------- gate: G = rmsnorm(y * silu(z)) * w  (bf16 y in, bf16 G out) ----------------
__global__ __launch_bounds__(256) void gate_kernel(
    float* __restrict__ XBC, const unsigned short* __restrict__ Zbf,
    const float* __restrict__ rms_w)
{
    int row = blockIdx.x * 4 + (threadIdx.x >> 6);
    int lane = threadIdx.x & 63;
    // y channel ch=lane*8..+7: h=lane>>1, p0=(lane&1)*8
    // ushort idx = (h>>3)*256 + (h&7)*16 + p0
    const unsigned short* yrow = (const unsigned short*)(XBC + (long long)row * XBCLD);
    int h = lane >> 1, pp = (lane & 1) * 8;
    int yidx = ((h >> 3) << 8) + ((h & 7) << 4) + pp;
    uint4 yq = *(const uint4*)(yrow + yidx);
    const unsigned short* zrow = Zbf + (long long)row * 512 + lane * 8;
    uint4 zq = ((const uint4*)zrow)[0];
    float yv[8];
    yv[0] = bf2f((unsigned short)(yq.x & 0xFFFF)); yv[1] = bf2f((unsigned short)(yq.x >> 16));
    yv[2] = bf2f((unsigned short)(yq.y & 0xFFFF)); yv[3] = bf2f((unsigned short)(yq.y >> 16));
    yv[4] = bf2f((unsigned short)(yq.z & 0xFFFF)); yv[5] = bf2f((unsigned short)(yq.z >> 16));
    yv[6] = bf2f((unsigned short)(yq.w & 0xFFFF)); yv[7] = bf2f((unsigned short)(yq.w >> 16));
    float zv[8];
    zv[0] = bf2f((unsigned short)(zq.x & 0xFFFF)); zv[1] = bf2f((unsigned short)(zq.x >> 16));
    zv[2] = bf2f((unsigned short)(zq.y & 0xFFFF)); zv[3] = bf2f((unsigned short)(zq.y >> 16));
    zv[4] = bf2f((unsigned short)(zq.z & 0xFFFF)); zv[5] = bf2f((unsigned short)(zq.z >> 16));
    zv[6] = bf2f((unsigned short)(zq.w & 0xFFFF)); zv[7] = bf2f((unsigned short)(zq.w >> 16));
    float a[8]; float ss = 0.f;
#pragma unroll
    for (int i = 0; i < 8; i++) {
        float z = zv[i];
        a[i] = yv[i] * (z * __builtin_amdgcn_rcpf(1.f + __expf(-z)));
        ss = fmaf(a[i], a[i], ss);
    }
#pragma unroll
    for (int m = 1; m < 64; m <<= 1) ss += __shfl_xor(ss, m);
    float sc = rsqrtf(ss * (1.f / 512.f) + 1e-5f);
    const float* rw = rms_w + lane * 8;
    float4 r0 = ((const float4*)rw)[0];
    float4 r1 = ((const float4*)rw)[1];
    float rv[8] = { r0.x, r0.y, r0.z, r0.w, r1.x, r1.y, r1.z, r1.w };
    uint4 o;
    o.x = (unsigned)f2bf(a[0] * sc * rv[0]) | ((unsigned)f2bf(a[1] * sc * rv[1]) << 16);
    o.y = (unsigned)f2bf(a[2] * sc * rv[2]) | ((unsigned)f2bf(a[3] * sc * rv[3]) << 16);
    o.z = (unsigned)f2bf(a[4] * sc * rv[4]) | ((unsigned)f2bf(a[5] * sc * rv[5]) << 16);
    o.w = (unsigned)f2bf(a[6] * sc * rv[6]) | ((unsigned)f2bf(a[7] * sc * rv[7]) << 16);
    unsigned short* grow = (unsigned short*)(XBC + (long long)row * XBCLD);
    ((uint4*)grow)[lane] = o;
}

// ---------------- LayerNorm(bf16 a + bf16 b)*g+be -> f32 ----------------
__global__ void lnadd_bb_kernel(const unsigned short* __restrict__ A, const unsigned short* __restrict__ Bb,
                                const float* __restrict__ g, const float* __restrict__ be,
                                float* __restrict__ O)
{
    int row = blockIdx.x * 4 + (threadIdx.x >> 6);
    int lane = threadIdx.x & 63;
    long long base = (long long)row * DMODEL + lane * 4;
    float v[4]; float s1 = 0.f;
#pragma unroll
    for (int i = 0; i < 4; i++) { float a = bf2f(A[base + i]) + bf2f(Bb[base + i]); v[i] = a; s1 += a; }
#pragma unroll
    for (int m = 1; m < 64; m <<= 1) s1 += __shfl_xor(s1, m);
    float mean = s1 * (1.f / 256.f);
    float s2 = 0.f;
#pragma unroll
    for (int i = 0; i < 4; i++) { float d = v[i] - mean; s2 = fmaf(d, d, s2); }
#pragma unroll
    for (int m = 1; m < 64; m <<= 1) s2 += __shfl_xor(s2, m);
    float r = rsqrtf(s2 * (1.f / 256.f) + 1e-12f);
#pragma unroll
    for (int i = 0; i < 4; i++)
        O[base + i] = (v[i] - mean) * r * g[lane * 4 + i] + be[lane * 4 + i];
}

// ---------------- fused: H = alpha*LN(MOb+x) + beta*LN(XI+x) -> bf16 HB ----------------
__global__ void combine2_kernel(const unsigned short* __restrict__ XI, const float* __restrict__ X,
                                const unsigned short* __restrict__ MOb, unsigned short* __restrict__ HB,
                                const float* __restrict__ lg, const float* __restrict__ lb,
                                const float* __restrict__ fg, const float* __restrict__ fb,
                                const float* __restrict__ al, const float* __restrict__ bt)
{
    int row = blockIdx.x * 4 + (threadIdx.x >> 6);
    int lane = threadIdx.x & 63;
    long long base = (long long)row * DMODEL + lane * 4;
    int bb = row / SEQ, ll = row - bb * SEQ;
    long long xib = (long long)bb * 65536 + ll * 256 + lane * 4;
    float u[4], v[4]; float su = 0.f, sv = 0.f;
#pragma unroll
    for (int i = 0; i < 4; i++) {
        float xv = X[base + i];
        float a = bf2f(MOb[base + i]) + xv;
        float b = bf2f(XI[xib + i]) + xv;
        u[i] = a; v[i] = b; su += a; sv += b;
    }
#pragma unroll
    for (int m = 1; m < 64; m <<= 1) { su += __shfl_xor(su, m); sv += __shfl_xor(sv, m); }
    float mu = su * (1.f / 256.f), mv = sv * (1.f / 256.f);
    float qu = 0.f, qv = 0.f;
#pragma unroll
    for (int i = 0; i < 4; i++) {
        float du = u[i] - mu; qu = fmaf(du, du, qu);
        float dv = v[i] - mv; qv = fmaf(dv, dv, qv);
    }
#pragma unroll
    for (int m = 1; m < 64; m <<= 1) { qu += __shfl_xor(qu, m); qv += __shfl_xor(qv, m); }
    float ru = rsqrtf(qu * (1.f / 256.f) + 1e-12f);
    float rv = rsqrtf(qv * (1.f / 256.f) + 1e-12f);
#pragma unroll
    for (int i = 0; i < 4; i++) {
        int d = lane * 4 + i;
        float h1 = (u[i] - mu) * ru * lg[d] + lb[d];
        float h2 = (v[i] - mv) * rv * fg[d] + fb[d];
        float h = al[d] * h1 + bt[d] * h2;
        HB[base + i] = f2bf(h);
    }
}

// ---------------- pointwise spectral filter on XFT[b][d][j] bf16 (ld 256) ----------------
__global__ void filt_kernel(unsigned short* __restrict__ XF, const float* __restrict__ W)
{
    long long idx = (long long)blockIdx.x * 256 + threadIdx.x;
    if (idx >= (long long)BATCHN * DMODEL * NF) return;
    int f = (int)(idx % NF);
    int d = (int)((idx / NF) % DMODEL);
    int b = (int)(idx / ((long long)NF * DMODEL));
    long long base = ((long long)b * DMODEL + d) * 256;
    float re = bf2f(XF[base + f]);
    float im = bf2f(XF[base + 101 + f]);
    float wr = W[((long long)f * DMODEL + d) * 2];
    float wi = W[((long long)f * DMODEL + d) * 2 + 1];
    XF[base + f]       = f2bf(re * wr - im * wi);
    XF[base + 101 + f] = f2bf(re * wi + im * wr);
}

extern "C" void kernel_launch(void* const* d_in, const int* in_sizes, int n_in,
                              void* d_out, int out_size, void* d_ws, size_t ws_size,
                              hipStream_t stream)
{
    const float* x          = (const float*)d_in[0];
    const float* in_proj_w  = (const float*)d_in[1];
    const float* conv_w     = (const float*)d_in[2];
    const float* conv_b     = (const float*)d_in[3];
    const float* dt_bias    = (const float*)d_in[4];
    const float* A_log      = (const float*)d_in[5];
    const float* D_skip     = (const float*)d_in[6];
    const float* rms_w      = (const float*)d_in[7];
    const float* out_proj_w = (const float*)d_in[8];
    const float* ln_g       = (const float*)d_in[9];
    const float* ln_b       = (const float*)d_in[10];
    const float* filt_w     = (const float*)d_in[11];
    const float* filt_ln_g  = (const float*)d_in[12];
    const float* filt_ln_b  = (const float*)d_in[13];
    const float* alpha      = (const float*)d_in[14];
    const float* beta       = (const float*)d_in[15];
    const float* ffn_w1     = (const float*)d_in[16];
    const float* ffn_b1     = (const float*)d_in[17];
    const float* ffn_w2     = (const float*)d_in[18];
    const float* ffn_b2     = (const float*)d_in[19];
    const float* ffn_ln_g   = (const float*)d_in[20];
    const float* ffn_ln_b   = (const float*)d_in[21];
    float* out = (float*)d_out;
    float* ws = (float*)d_ws;

    // weights arena [81920 .. XBASE)
    unsigned short* WP    = (unsigned short*)(ws + 81920);
    unsigned short* wTall = WP;                  // 1184*256
    unsigned short* opwT  = wTall + 1184 * 256;  // 256*512
    unsigned short* w1T   = opwT + 256 * 512;    // 1024*256
    unsigned short* w2T   = w1T + 1024 * 256;    // 256*1024
    unsigned short* EFbf  = w2T + 256 * 1024;    // 256*200
    unsigned short* EIbf  = EFbf + 256 * SEQ;    // 256*256
    float* XBC = ws + XBASE;                     // BL*672 f32 arena
    float* BCb = XBC + (long long)BL * XBCLD;    // BL*128
    float* DTb = BCb + (long long)BL * 128;      // BL*32
    float* DAb = DTb + (long long)BL * NH;       // BL*32
    float* MO  = DAb + (long long)BL * NH;       // BL*256 region (Zbf / MOb)
    float* BCF = MO + (long long)BL * DMODEL;    // BL  (b·c per row)
    unsigned short* Zbf = (unsigned short*)MO;   // BL*512 bf16, lifetime [proj..gate]
    unsigned short* MOb = (unsigned short*)MO;   // BL*512 bf16 (only 256 used/row), [out_proj..combine2]
    // BCb region reuse:
    unsigned short* xbf  = (unsigned short*)BCb; // bf16 x, lifetime [setup..proj]
    unsigned short* xTbf = (unsigned short*)BCb; // lifetime [xT..FFT fwd]
    unsigned short* MObf = (unsigned short*)BCb; // bf16 H, lifetime [combine2..lnadd_bb]
    // XBC arena reuse:
    unsigned short* Gbf = (unsigned short*)XBC;              // bf16 G in place, ld 1344
    unsigned short* XFT = (unsigned short*)XBC;              // 256*256*256 bf16
    unsigned short* XI  = (unsigned short*)(XBC + XIOFF);    // 256*65536 bf16
    unsigned short* HID = (unsigned short*)XBC;              // BL*1024 bf16 (post-combine2)
    unsigned short* FFO = (unsigned short*)(XBC + 26500000); // BL*256 bf16

    // 1. DFT matrices + merged setup (packs + x->bf16)
    init_dft_kernel<<<dim3((256 * SEQ + 256 * 256 + 255) / 256), dim3(256), 0, stream>>>(EFbf, EIbf);
    setup_kernel<<<dim3((S0 + S1 + S2 + S3 + S4) / 256), dim3(256), 0, stream>>>(
        in_proj_w, out_proj_w, ffn_w1, ffn_w2, x, wTall, opwT, w1T, w2T, xbf);

    // 2. merged projection: xbf[BL,256] @ wTall^T -> Zbf (cols<512) + XBC (cols>=512)
    mgemm_proj<<<dim3(10, BL / 128), dim3(256), 0, stream>>>(xbf, wTall, XBC, Zbf);

    // 3. conv+silu B/C; dt -> DT/DA; bc -> BCF (clobbers xbf)
    convbc2_kernel<<<dim3(BATCHN * 8), dim3(256), 0, stream>>>(XBC, conv_w, conv_b, dt_bias,
                                                               A_log, BCb, DTb, DAb, BCF);

    // 4. scan v7b, y bf16 packed in place
    scan7b_kernel<<<dim3(BATCHN * 4), dim3(256), 0, stream>>>(DTb, DAb, XBC, BCb, D_skip,
                                                              conv_w, conv_b, BCF);

    // 4.5 x transpose -> xTbf (BCb dead after scan)
    xT_kernel<<<dim3(7, 8, BATCHN), dim3(256), 0, stream>>>(x, xTbf);

    // 5. gate -> Gbf bf16 in place (reads packed y + Zbf)
    gate_kernel<<<dim3(BL / 4), dim3(256), 0, stream>>>(XBC, Zbf, rms_w);

    // 6. out_proj: Gbf[BL,512](ld 1344) @ opwT^T -> MOb bf16 (Zbf dead)
    mgemm_kernel<0,1><<<dim3(2, BL / 128, 1), dim3(256), 0, stream>>>(
        Gbf, opwT, MOb, nullptr, BL, 256, 512, 1344, 512, 256, 0, 0, 0);

    // 7. FFT fwd: XFT[b][256][256] = xTbf[b][256,200] @ EFbf[256,200]^T, bf16 (ld 256)
    mgemm_kernel<0,1><<<dim3(2, 2, BATCHN), dim3(256), 0, stream>>>(
        xTbf, EFbf, XFT, nullptr, 256, 256, SEQ, SEQ, SEQ, 256,
        (long long)DMODEL * SEQ, 0, 65536);

    // 8. spectral filter in place
    filt_kernel<<<dim3((BATCHN * DMODEL * NF + 255) / 256), dim3(256), 0, stream>>>(XFT, filt_w);

    // 9. FFT inv: XI[b][256][256] = EIbf[256,256] @ XFT[b]^T, bf16 out (batch stride 65536)
    mgemm_kernel<0,1><<<dim3(2, 2, BATCHN), dim3(256), 0, stream>>>(
        EIbf, XFT, XI, nullptr, 256, 256, 256, 256, 256, 256,
        0, 65536, 65536);

    // 10. fused combine -> bf16 H only (MObf; xTbf dead)
    combine2_kernel<<<dim3(BL / 4), dim3(256), 0, stream>>>(XI, x, MOb, MObf,
                                                            ln_g, ln_b, filt_ln_g, filt_ln_b,
                                                            alpha, beta);

    // 11. FFN1: MObf[BL,256] @ w1T^T + b1, GELU -> HID bf16 (XI dead)
    mgemm_kernel<1,1><<<dim3(8, BL / 128, 1), dim3(256), 0, stream>>>(
        MObf, w1T, HID, ffn_b1, BL, 1024, 256, 256, 256, 1024, 0, 0, 0);

    // 12. FFN2: HID[BL,1024] @ w2T^T + b2 -> FFO bf16
    mgemm_kernel<0,1><<<dim3(2, BL / 128, 1), dim3(256), 0, stream>>>(
        HID, w2T, FFO, ffn_b2, BL, 256, 1024, 1024, 1024, 256, 0, 0, 0);

    // 13. out = LN(FFO + H)
    lnadd_bb_kernel<<<dim3(BL / 4), dim3(256), 0, stream>>>(FFO, MObf, ffn_ln_g, ffn_ln_b, out);
}